// Round 1
// baseline (1410.237 us; speedup 1.0000x reference)
//
#include <hip/hip_runtime.h>
#include <cstdint>
#include <cstddef>

#define ALPHA_ 0.1f

static inline int cdiv(int a, int b) { return (a + b - 1) / b; }

// ---------------- GEMM core: acc = A(N x K) @ W(K x 128), per-thread column ----------------
// 256 threads: col = tid & 127, row-half = tid >> 7 (wave-uniform via readfirstlane).
// A loads are wave-uniform -> scalar s_load; W loads are coalesced vector loads (L2-hot).
template<int TR>
__device__ __forceinline__ void gemm_acc(const float* __restrict__ A, const float* __restrict__ W,
                                         int N, int K, int row0, int col, float* acc)
{
  const float* arow[TR];
#pragma unroll
  for (int r = 0; r < TR; ++r) {
    int rr = row0 + r; if (rr > N - 1) rr = N - 1;   // clamp (dup work, guarded store)
    arow[r] = A + (size_t)rr * K;
  }
#pragma unroll
  for (int r = 0; r < TR; ++r) acc[r] = 0.f;

  for (int k = 0; k < K; k += 8) {   // K always a multiple of 8 here (8000/6000/128)
    float w[8];
#pragma unroll
    for (int kk = 0; kk < 8; ++kk) w[kk] = W[(size_t)(k + kk) * 128 + col];
#pragma unroll
    for (int r = 0; r < TR; ++r) {
      const float* ap = arow[r] + k;
#pragma unroll
      for (int kk = 0; kk < 8; ++kk) acc[r] = fmaf(ap[kk], w[kk], acc[r]);
    }
  }
}

// Both init GEMMs in one launch for occupancy: C[0:Nm) = miRNA@Wm, C[Nm:Nm+Nd) = disease@Wd
template<int TR>
__global__ __launch_bounds__(256) void init_gemm2(
    const float* __restrict__ Am, const float* __restrict__ Wma, int Nm_,
    const float* __restrict__ Ad, const float* __restrict__ Wda, int Nd_,
    float* __restrict__ C)
{
  const int col = threadIdx.x & 127;
  const int rh  = __builtin_amdgcn_readfirstlane((int)(threadIdx.x >> 7));
  int bid = blockIdx.x;
  const int nbm = Nm_ / (2 * TR);
  const float* A; const float* W; int N, K, rowbase;
  if (bid < nbm) { A = Am; W = Wma; N = Nm_; K = Nm_; rowbase = 0; }
  else          { bid -= nbm; A = Ad; W = Wda; N = Nd_; K = Nd_; rowbase = Nm_; }
  const int row0 = bid * (2 * TR) + rh * TR;
  float acc[TR];
  gemm_acc<TR>(A, W, N, K, row0, col, acc);
#pragma unroll
  for (int r = 0; r < TR; ++r) {
    int rr = row0 + r;
    if (rr < N) C[(size_t)(rowbase + rr) * 128 + col] = acc[r];
  }
}

// out = ALPHA*init + (1-ALPHA)*relu(R @ fcW)   (R: N x 128, fcW: 128 x 128)
template<int TR>
__global__ __launch_bounds__(256) void fc_residual(
    const float* __restrict__ Rm, const float* __restrict__ W,
    const float* __restrict__ initb, float* __restrict__ C, int N)
{
  const int col = threadIdx.x & 127;
  const int rh  = __builtin_amdgcn_readfirstlane((int)(threadIdx.x >> 7));
  const int row0 = blockIdx.x * (2 * TR) + rh * TR;
  float acc[TR];
  gemm_acc<TR>(Rm, W, N, 128, row0, col, acc);
#pragma unroll
  for (int r = 0; r < TR; ++r) {
    int rr = row0 + r;
    if (rr < N) {
      size_t o = (size_t)rr * 128 + col;
      C[o] = ALPHA_ * initb[o] + (1.f - ALPHA_) * fmaxf(acc[r], 0.f);
    }
  }
}

// r[n,d] = (1/P) * sum_p sum_l feats[paths[p,n,l], d] * pw[l, d]
template<int L>
__global__ __launch_bounds__(256) void gather_einsum(
    const float* __restrict__ feats, const int* __restrict__ paths,
    const float* __restrict__ pw, float* __restrict__ r, int N, int P)
{
  const int d = threadIdx.x & 127;
  const int nsub = __builtin_amdgcn_readfirstlane((int)(threadIdx.x >> 7));
  const int n = blockIdx.x * 2 + nsub;
  if (n >= N) return;
  float pwv[L];
#pragma unroll
  for (int l = 0; l < L; ++l) pwv[l] = pw[l * 128 + d];
  float acc = 0.f;
  for (int p = 0; p < P; ++p) {
    const int* ip = paths + ((size_t)p * N + n) * L;   // wave-uniform -> scalar loads
    int idx[L];
#pragma unroll
    for (int l = 0; l < L; ++l) idx[l] = ip[l];
#pragma unroll
    for (int l = 0; l < L; ++l)
      acc = fmaf(pwv[l], feats[(size_t)idx[l] * 128 + d], acc);
  }
  r[(size_t)n * 128 + d] = acc * (1.0f / (float)P);
}

// runtime-L fallback (not expected to be used for L in {4,6})
__global__ __launch_bounds__(256) void gather_einsum_rt(
    const float* __restrict__ feats, const int* __restrict__ paths,
    const float* __restrict__ pw, float* __restrict__ r, int N, int P, int L)
{
  const int d = threadIdx.x & 127;
  const int n = blockIdx.x * 2 + (threadIdx.x >> 7);
  if (n >= N) return;
  float acc = 0.f;
  for (int p = 0; p < P; ++p) {
    const int* ip = paths + ((size_t)p * N + n) * L;
    for (int l = 0; l < L; ++l)
      acc = fmaf(pw[l * 128 + d], feats[(size_t)ip[l] * 128 + d], acc);
  }
  r[(size_t)n * 128 + d] = acc * (1.0f / (float)P);
}

// MLP collapse stage 1: w01 = W0(E x K0) @ W1(K0 x H1); b01 = b0 @ W1 + b1
__global__ void collapse1(const float* __restrict__ W0, const float* __restrict__ b0,
                          const float* __restrict__ W1, const float* __restrict__ b1,
                          float* __restrict__ w01, float* __restrict__ b01,
                          int E, int K0, int H1)
{
  int row = blockIdx.x; int c = threadIdx.x;
  if (c >= H1) return;
  const float* src; float acc;
  if (row < E) { src = W0 + (size_t)row * K0; acc = 0.f; }
  else         { src = b0; acc = b1[c]; }
  for (int k = 0; k < K0; ++k) acc = fmaf(src[k], W1[(size_t)k * H1 + c], acc);
  if (row < E) w01[(size_t)row * H1 + c] = acc; else b01[c] = acc;
}

// MLP collapse stage 2: w512 = w01 @ W2; c = b01 @ W2 + b2
__global__ void collapse2(const float* __restrict__ w01, const float* __restrict__ b01,
                          const float* __restrict__ W2, const float* __restrict__ b2,
                          float* __restrict__ w512, float* __restrict__ csc,
                          int E, int H1)
{
  int i = blockIdx.x * blockDim.x + threadIdx.x;
  if (i < E) {
    float a = 0.f;
    for (int j = 0; j < H1; ++j) a = fmaf(w01[(size_t)i * H1 + j], W2[j], a);
    w512[i] = a;
  } else if (i == E) {
    float a = b2[0];
    for (int j = 0; j < H1; ++j) a = fmaf(b01[j], W2[j], a);
    csc[0] = a;
  }
}

// Per-node partial dots: node<Nm: u = Fmm[i].w[0:128] + Fmd[i].w[128:256]
//                        node>=Nm: v = Fdd[j].w[256:384] + Fmd[node].w[384:512]
__global__ __launch_bounds__(256) void node_partial(
    const float* __restrict__ Fmm, const float* __restrict__ Fdd, const float* __restrict__ Fmd,
    const float* __restrict__ w512, float* __restrict__ uv, int Nm, int Nt)
{
  int gid = blockIdx.x * blockDim.x + threadIdx.x;
  int wid = gid >> 6;
  int lane = threadIdx.x & 63;
  if (wid >= Nt) return;
  bool isM = wid < Nm;
  const float* X = isM ? (Fmm + (size_t)wid * 128) : (Fdd + (size_t)(wid - Nm) * 128);
  const float* Y = Fmd + (size_t)wid * 128;
  const float* w1 = w512 + (isM ? 0 : 256);
  const float* w2 = w1 + 128;
  float s = fmaf(X[lane], w1[lane], 0.f);
  s = fmaf(X[lane + 64], w1[lane + 64], s);
  s = fmaf(Y[lane], w2[lane], s);
  s = fmaf(Y[lane + 64], w2[lane + 64], s);
#pragma unroll
  for (int off = 32; off > 0; off >>= 1) s += __shfl_down(s, off);
  if (lane == 0) uv[wid] = s;
}

__global__ __launch_bounds__(256) void score_kernel(
    const int* __restrict__ samples, const float* __restrict__ u, const float* __restrict__ v,
    const float* __restrict__ csc, float* __restrict__ out, int S)
{
  int s = blockIdx.x * blockDim.x + threadIdx.x;
  if (s >= S) return;
  const int2 ij = ((const int2*)samples)[s];
  float x = u[ij.x] + v[ij.y] + csc[0];
  out[s] = 1.0f / (1.0f + expf(-x));
}

extern "C" void kernel_launch(void* const* d_in, const int* in_sizes, int n_in,
                              void* d_out, int out_size, void* d_ws, size_t ws_size,
                              hipStream_t stream)
{
  const int*   paths_mm = (const int*)d_in[0];
  const int*   paths_dd = (const int*)d_in[1];
  const int*   paths_md = (const int*)d_in[2];
  const float* miRNA    = (const float*)d_in[3];
  const float* disease  = (const float*)d_in[4];
  const int*   samples  = (const int*)d_in[5];
  const float* Wm  = (const float*)d_in[6];
  const float* Wd  = (const float*)d_in[7];
  const float* pw1 = (const float*)d_in[8];
  const float* pw2 = (const float*)d_in[9];
  const float* fcW = (const float*)d_in[10];
  const float* W0  = (const float*)d_in[11];
  const float* b0  = (const float*)d_in[12];
  const float* W1  = (const float*)d_in[13];
  const float* b1  = (const float*)d_in[14];
  const float* W2  = (const float*)d_in[15];
  const float* b2  = (const float*)d_in[16];

  const int D  = 128;
  const int Nm = in_sizes[6] / D;
  const int Nd = in_sizes[7] / D;
  const int Nt = Nm + Nd;
  const int S  = in_sizes[5] / 2;
  const int layers = in_sizes[10] / (D * D);
  const int L1 = in_sizes[8] / (layers * D);
  const int L2 = in_sizes[9] / (layers * D);
  const int P  = in_sizes[0] / (Nm * L1);
  const int E  = 4 * D;                 // 512
  const int K0 = in_sizes[12];          // 256
  const int H1 = in_sizes[14];          // 64

  float* out = (float*)d_out;
  float* ws  = (float*)d_ws;
  size_t off = 0;
  float* init = ws + off; off += (size_t)Nt * D;
  float* bufA = ws + off; off += (size_t)Nt * D;
  float* bufR = ws + off; off += (size_t)Nt * D;
  float* Fmm  = ws + off; off += (size_t)Nm * D;
  float* Fdd  = ws + off; off += (size_t)Nd * D;
  float* Fmd  = ws + off; off += (size_t)Nt * D;
  float* w01  = ws + off; off += (size_t)E * H1;
  float* b01  = ws + off; off += H1;
  float* w512 = ws + off; off += E;
  float* csc  = ws + off; off += 1;
  float* uv   = ws + off; off += Nt;
  (void)ws_size; (void)n_in; (void)out_size;

  constexpr int TR = 8;                 // 16 rows per block
  const int RB = 2 * TR;

  // 1. init features (both GEMMs fused into one grid)
  {
    int grid = Nm / RB + Nd / RB;
    init_gemm2<TR><<<grid, 256, 0, stream>>>(miRNA, Wm, Nm, disease, Wd, Nd, init);
  }

  // 2. MLP collapse (independent of features)
  collapse1<<<E + 1, 64, 0, stream>>>(W0, b0, W1, b1, w01, b01, E, K0, H1);
  collapse2<<<cdiv(E + 1, 256), 256, 0, stream>>>(w01, b01, W2, b2, w512, csc, E, H1);

  // 3. three path-layer chains
  struct Chain { const float* base; const int* paths; const float* pw; int N; int L; float* fin; };
  Chain chains[3] = {
    { init,                paths_mm, pw1, Nm, L1, Fmm },
    { init + (size_t)Nm*D, paths_dd, pw1, Nd, L1, Fdd },
    { init,                paths_md, pw2, Nt, L2, Fmd },
  };
  for (int ci = 0; ci < 3; ++ci) {
    Chain& ch = chains[ci];
    const float* cur = ch.base;
    for (int l = 0; l < layers; ++l) {
      const float* pwl = ch.pw + (size_t)l * ch.L * D;
      int ggrid = cdiv(ch.N, 2);
      if (ch.L == 4)      gather_einsum<4><<<ggrid, 256, 0, stream>>>(cur, ch.paths, pwl, bufR, ch.N, P);
      else if (ch.L == 6) gather_einsum<6><<<ggrid, 256, 0, stream>>>(cur, ch.paths, pwl, bufR, ch.N, P);
      else                gather_einsum_rt<<<ggrid, 256, 0, stream>>>(cur, ch.paths, pwl, bufR, ch.N, P, ch.L);
      float* dst = (l == layers - 1) ? ch.fin : bufA;
      fc_residual<TR><<<cdiv(ch.N, RB), 256, 0, stream>>>(bufR, fcW + (size_t)l * D * D, ch.base, dst, ch.N);
      cur = dst;
    }
  }

  // 4. per-node partial dots with collapsed MLP vector
  node_partial<<<cdiv(Nt * 64, 256), 256, 0, stream>>>(Fmm, Fdd, Fmd, w512, uv, Nm, Nt);

  // 5. score 200k samples: sigmoid(u[i] + v[j] + c)
  score_kernel<<<cdiv(S, 256), 256, 0, stream>>>(samples, uv, uv + Nm, csc, out, S);
}

// Round 2
// 694.017 us; speedup vs baseline: 2.0320x; 2.0320x over previous
//
#include <hip/hip_runtime.h>
#include <hip/hip_bf16.h>
#include <cstdint>
#include <cstddef>

#define ALPHA_ 0.1f

static inline int cdiv(int a, int b) { return (a + b - 1) / b; }

typedef __attribute__((ext_vector_type(8))) short short8;
typedef __attribute__((ext_vector_type(4))) float float4v;

// ---------------- Wt builder: Wt[c][k] = bf16(W[k][c]), zero-padded to Kpad ----------------
__global__ __launch_bounds__(256) void make_wt(const float* __restrict__ W,
                                               __hip_bfloat16* __restrict__ Wt,
                                               int K, int Kpad)
{
  const int c = blockIdx.y;                    // 0..127
  const int k = blockIdx.x * 256 + threadIdx.x;
  if (k >= Kpad) return;
  float v = (k < K) ? W[(size_t)k * 128 + c] : 0.f;
  Wt[(size_t)c * Kpad + k] = __float2bfloat16(v);
}

// ---------------- init GEMM via MFMA: C = A(NxK) @ W(Kx128), computed as C^T = Wt @ A^T ----
// Block: 256 thr = 4 waves; wave w owns rows [rb*64 + w*16, +16), all 128 cols (8 m-tiles).
// Split-K: chunk c writes partial buffer p[c]; combine3 sums them.
template<int KSPLIT>
__global__ __launch_bounds__(256) void init_mfma(
    const float* __restrict__ Am, const __hip_bfloat16* __restrict__ Wtm, int Nm_, int Km, int nbm,
    const float* __restrict__ Ad, const __hip_bfloat16* __restrict__ Wtd, int Nd_, int Kd, int Kpd,
    float* __restrict__ p0, float* __restrict__ p1, float* __restrict__ p2)
{
  const int lane = threadIdx.x & 63;
  const int wv   = threadIdx.x >> 6;
  const int nbd_total = gridDim.x / KSPLIT;       // nbm + nbd
  int mb    = blockIdx.x % nbd_total;
  int chunk = blockIdx.x / nbd_total;

  const float* A; const __hip_bfloat16* Wt; int N, K, Kpad, rowoff, rb;
  if (mb < nbm) { A = Am; Wt = Wtm; N = Nm_; K = Km; Kpad = Km;  rowoff = 0;   rb = mb; }
  else          { A = Ad; Wt = Wtd; N = Nd_; K = Kd; Kpad = Kpd; rowoff = Nm_; rb = mb - nbm; }

  float* Cp = (chunk == 0) ? p0 : (chunk == 1) ? p1 : p2;

  const int St = Kpad / 32;
  const int s0 = (St * chunk) / KSPLIT;
  const int s1 = (St * (chunk + 1)) / KSPLIT;

  const int row0 = rb * 64 + wv * 16;
  const int rloc = lane & 15;          // fragment row / output row
  const int kg   = (lane >> 4) * 8;    // k sub-offset within 32

  int r  = row0 + rloc;
  int ra = (r < N) ? r : (N - 1);      // clamp loads, guard stores
  const float* arow = A + (size_t)ra * K;
  const __hip_bfloat16* wbase = Wt + (size_t)rloc * Kpad + kg;

  float4v acc[8];
#pragma unroll
  for (int mt = 0; mt < 8; ++mt) acc[mt] = (float4v){0.f, 0.f, 0.f, 0.f};

  for (int s = s0; s < s1; ++s) {
    const int k0 = s * 32;
    const int k  = k0 + kg;
    // ---- B operand: A rows, f32 -> bf16 in-register ----
    float f[8];
    if (k + 8 <= K) {
      float4v t0 = *(const float4v*)(arow + k);
      float4v t1 = *(const float4v*)(arow + k + 4);
      f[0]=t0.x; f[1]=t0.y; f[2]=t0.z; f[3]=t0.w;
      f[4]=t1.x; f[5]=t1.y; f[6]=t1.z; f[7]=t1.w;
    } else {
#pragma unroll
      for (int j = 0; j < 8; ++j) f[j] = (k + j < K) ? arow[k + j] : 0.f;
    }
    union { short8 v; __hip_bfloat16 h[8]; } bb;
#pragma unroll
    for (int j = 0; j < 8; ++j) bb.h[j] = __float2bfloat16(f[j]);

    // ---- A operand: Wt fragments (bf16, L2-hot), 8 m-tiles ----
#pragma unroll
    for (int mt = 0; mt < 8; ++mt) {
      short8 a = *(const short8*)(wbase + (size_t)mt * 16 * Kpad + k0);
      acc[mt] = __builtin_amdgcn_mfma_f32_16x16x32_bf16(a, bb.v, acc[mt], 0, 0, 0);
    }
  }

  if (r < N) {
    float* dst = Cp + ((size_t)(rowoff + r)) * 128 + (lane >> 4) * 4;
#pragma unroll
    for (int mt = 0; mt < 8; ++mt)
      *(float4v*)(dst + mt * 16) = acc[mt];
  }
}

__global__ __launch_bounds__(256) void combine3(const float4v* __restrict__ a,
                                                const float4v* __restrict__ b,
                                                const float4v* __restrict__ c,
                                                float4v* __restrict__ o, int n4)
{
  int i = blockIdx.x * 256 + threadIdx.x;
  if (i < n4) {
    float4v x = a[i], y = b[i], z = c[i];
    o[i] = (float4v){x.x + y.x + z.x, x.y + y.y + z.y, x.z + y.z + z.z, x.w + y.w + z.w};
  }
}

// ---------------- f32 GEMV core for the small fc layers ----------------
template<int TR>
__device__ __forceinline__ void gemm_acc(const float* __restrict__ A, const float* __restrict__ W,
                                         int N, int K, int row0, int col, float* acc)
{
  const float* arow[TR];
#pragma unroll
  for (int r = 0; r < TR; ++r) {
    int rr = row0 + r; if (rr > N - 1) rr = N - 1;
    arow[r] = A + (size_t)rr * K;
  }
#pragma unroll
  for (int r = 0; r < TR; ++r) acc[r] = 0.f;

  for (int k = 0; k < K; k += 8) {
    float w[8];
#pragma unroll
    for (int kk = 0; kk < 8; ++kk) w[kk] = W[(size_t)(k + kk) * 128 + col];
#pragma unroll
    for (int r = 0; r < TR; ++r) {
      const float* ap = arow[r] + k;
#pragma unroll
      for (int kk = 0; kk < 8; ++kk) acc[r] = fmaf(ap[kk], w[kk], acc[r]);
    }
  }
}

// out = ALPHA*init + (1-ALPHA)*relu(R @ fcW)
template<int TR>
__global__ __launch_bounds__(256) void fc_residual(
    const float* __restrict__ Rm, const float* __restrict__ W,
    const float* __restrict__ initb, float* __restrict__ C, int N)
{
  const int col = threadIdx.x & 127;
  const int rh  = __builtin_amdgcn_readfirstlane((int)(threadIdx.x >> 7));
  const int row0 = blockIdx.x * (2 * TR) + rh * TR;
  float acc[TR];
  gemm_acc<TR>(Rm, W, N, 128, row0, col, acc);
#pragma unroll
  for (int r = 0; r < TR; ++r) {
    int rr = row0 + r;
    if (rr < N) {
      size_t o = (size_t)rr * 128 + col;
      C[o] = ALPHA_ * initb[o] + (1.f - ALPHA_) * fmaxf(acc[r], 0.f);
    }
  }
}

// r[n,d] = (1/P) * sum_p sum_l feats[paths[p,n,l], d] * pw[l, d]
template<int L>
__global__ __launch_bounds__(256) void gather_einsum(
    const float* __restrict__ feats, const int* __restrict__ paths,
    const float* __restrict__ pw, float* __restrict__ r, int N, int P)
{
  const int d = threadIdx.x & 127;
  const int nsub = __builtin_amdgcn_readfirstlane((int)(threadIdx.x >> 7));
  const int n = blockIdx.x * 2 + nsub;
  if (n >= N) return;
  float pwv[L];
#pragma unroll
  for (int l = 0; l < L; ++l) pwv[l] = pw[l * 128 + d];
  float acc = 0.f;
  for (int p = 0; p < P; ++p) {
    const int* ip = paths + ((size_t)p * N + n) * L;
    int idx[L];
#pragma unroll
    for (int l = 0; l < L; ++l) idx[l] = ip[l];
#pragma unroll
    for (int l = 0; l < L; ++l)
      acc = fmaf(pwv[l], feats[(size_t)idx[l] * 128 + d], acc);
  }
  r[(size_t)n * 128 + d] = acc * (1.0f / (float)P);
}

__global__ __launch_bounds__(256) void gather_einsum_rt(
    const float* __restrict__ feats, const int* __restrict__ paths,
    const float* __restrict__ pw, float* __restrict__ r, int N, int P, int L)
{
  const int d = threadIdx.x & 127;
  const int n = blockIdx.x * 2 + (threadIdx.x >> 7);
  if (n >= N) return;
  float acc = 0.f;
  for (int p = 0; p < P; ++p) {
    const int* ip = paths + ((size_t)p * N + n) * L;
    for (int l = 0; l < L; ++l)
      acc = fmaf(pw[l * 128 + d], feats[(size_t)ip[l] * 128 + d], acc);
  }
  r[(size_t)n * 128 + d] = acc * (1.0f / (float)P);
}

// MLP collapse stage 1: w01 = W0(E x K0) @ W1(K0 x H1); b01 = b0 @ W1 + b1
__global__ void collapse1(const float* __restrict__ W0, const float* __restrict__ b0,
                          const float* __restrict__ W1, const float* __restrict__ b1,
                          float* __restrict__ w01, float* __restrict__ b01,
                          int E, int K0, int H1)
{
  int row = blockIdx.x; int c = threadIdx.x;
  if (c >= H1) return;
  const float* src; float acc;
  if (row < E) { src = W0 + (size_t)row * K0; acc = 0.f; }
  else         { src = b0; acc = b1[c]; }
  for (int k = 0; k < K0; ++k) acc = fmaf(src[k], W1[(size_t)k * H1 + c], acc);
  if (row < E) w01[(size_t)row * H1 + c] = acc; else b01[c] = acc;
}

// MLP collapse stage 2: w512 = w01 @ W2; c = b01 @ W2 + b2
__global__ void collapse2(const float* __restrict__ w01, const float* __restrict__ b01,
                          const float* __restrict__ W2, const float* __restrict__ b2,
                          float* __restrict__ w512, float* __restrict__ csc,
                          int E, int H1)
{
  int i = blockIdx.x * blockDim.x + threadIdx.x;
  if (i < E) {
    float a = 0.f;
    for (int j = 0; j < H1; ++j) a = fmaf(w01[(size_t)i * H1 + j], W2[j], a);
    w512[i] = a;
  } else if (i == E) {
    float a = b2[0];
    for (int j = 0; j < H1; ++j) a = fmaf(b01[j], W2[j], a);
    csc[0] = a;
  }
}

__global__ __launch_bounds__(256) void node_partial(
    const float* __restrict__ Fmm, const float* __restrict__ Fdd, const float* __restrict__ Fmd,
    const float* __restrict__ w512, float* __restrict__ uv, int Nm, int Nt)
{
  int gid = blockIdx.x * blockDim.x + threadIdx.x;
  int wid = gid >> 6;
  int lane = threadIdx.x & 63;
  if (wid >= Nt) return;
  bool isM = wid < Nm;
  const float* X = isM ? (Fmm + (size_t)wid * 128) : (Fdd + (size_t)(wid - Nm) * 128);
  const float* Y = Fmd + (size_t)wid * 128;
  const float* w1 = w512 + (isM ? 0 : 256);
  const float* w2 = w1 + 128;
  float s = fmaf(X[lane], w1[lane], 0.f);
  s = fmaf(X[lane + 64], w1[lane + 64], s);
  s = fmaf(Y[lane], w2[lane], s);
  s = fmaf(Y[lane + 64], w2[lane + 64], s);
#pragma unroll
  for (int off = 32; off > 0; off >>= 1) s += __shfl_down(s, off);
  if (lane == 0) uv[wid] = s;
}

__global__ __launch_bounds__(256) void score_kernel(
    const int* __restrict__ samples, const float* __restrict__ u, const float* __restrict__ v,
    const float* __restrict__ csc, float* __restrict__ out, int S)
{
  int s = blockIdx.x * blockDim.x + threadIdx.x;
  if (s >= S) return;
  const int2 ij = ((const int2*)samples)[s];
  float x = u[ij.x] + v[ij.y] + csc[0];
  out[s] = 1.0f / (1.0f + expf(-x));
}

extern "C" void kernel_launch(void* const* d_in, const int* in_sizes, int n_in,
                              void* d_out, int out_size, void* d_ws, size_t ws_size,
                              hipStream_t stream)
{
  const int*   paths_mm = (const int*)d_in[0];
  const int*   paths_dd = (const int*)d_in[1];
  const int*   paths_md = (const int*)d_in[2];
  const float* miRNA    = (const float*)d_in[3];
  const float* disease  = (const float*)d_in[4];
  const int*   samples  = (const int*)d_in[5];
  const float* Wm  = (const float*)d_in[6];
  const float* Wd  = (const float*)d_in[7];
  const float* pw1 = (const float*)d_in[8];
  const float* pw2 = (const float*)d_in[9];
  const float* fcW = (const float*)d_in[10];
  const float* W0  = (const float*)d_in[11];
  const float* b0  = (const float*)d_in[12];
  const float* W1  = (const float*)d_in[13];
  const float* b1  = (const float*)d_in[14];
  const float* W2  = (const float*)d_in[15];
  const float* b2  = (const float*)d_in[16];

  const int D  = 128;
  const int Nm = in_sizes[6] / D;
  const int Nd = in_sizes[7] / D;
  const int Nt = Nm + Nd;
  const int S  = in_sizes[5] / 2;
  const int layers = in_sizes[10] / (D * D);
  const int L1 = in_sizes[8] / (layers * D);
  const int L2 = in_sizes[9] / (layers * D);
  const int P  = in_sizes[0] / (Nm * L1);
  const int E  = 4 * D;
  const int K0 = in_sizes[12];
  const int H1 = in_sizes[14];
  const int Kpm = cdiv(Nm, 32) * 32;    // 8000 (already mult of 32)
  const int Kpd = cdiv(Nd, 32) * 32;    // 6016

  float* out = (float*)d_out;
  float* ws  = (float*)d_ws;
  size_t off = 0;
  float* init = ws + off; off += (size_t)Nt * D;
  float* bufA = ws + off; off += (size_t)Nt * D;
  float* bufR = ws + off; off += (size_t)Nt * D;
  float* Fmm  = ws + off; off += (size_t)Nm * D;
  float* Fdd  = ws + off; off += (size_t)Nd * D;
  float* Fmd  = ws + off; off += (size_t)Nt * D;
  float* w01  = ws + off; off += (size_t)E * H1;
  float* b01  = ws + off; off += H1;
  float* w512 = ws + off; off += E;
  float* csc  = ws + off; off += 1;
  float* uv   = ws + off; off += Nt;
  __hip_bfloat16* Wtm = (__hip_bfloat16*)(ws + off); off += (size_t)D * Kpm / 2;
  __hip_bfloat16* Wtd = (__hip_bfloat16*)(ws + off); off += (size_t)D * Kpd / 2;
  (void)ws_size; (void)n_in; (void)out_size;

  // 1. build col-major bf16 weight transposes (tiny, L2-resident afterwards)
  {
    dim3 g1(cdiv(Kpm, 256), D); make_wt<<<g1, 256, 0, stream>>>(Wm, Wtm, Nm, Kpm);
    dim3 g2(cdiv(Kpd, 256), D); make_wt<<<g2, 256, 0, stream>>>(Wd, Wtd, Nd, Kpd);
  }

  // 2. MLP collapse (independent)
  collapse1<<<E + 1, 64, 0, stream>>>(W0, b0, W1, b1, w01, b01, E, K0, H1);
  collapse2<<<cdiv(E + 1, 256), 256, 0, stream>>>(w01, b01, W2, b2, w512, csc, E, H1);

  // 3. init features via MFMA, split-K=3 into init/bufA/bufR, then combine
  {
    constexpr int KSPLIT = 3;
    int nbm = cdiv(Nm, 64), nbd = cdiv(Nd, 64);
    int grid = (nbm + nbd) * KSPLIT;
    init_mfma<KSPLIT><<<grid, 256, 0, stream>>>(
        miRNA, Wtm, Nm, Nm, nbm, disease, Wtd, Nd, Nd, Kpd,
        init, bufA, bufR);
    int n4 = Nt * D / 4;
    combine3<<<cdiv(n4, 256), 256, 0, stream>>>(
        (const float4v*)init, (const float4v*)bufA, (const float4v*)bufR,
        (float4v*)init, n4);
  }

  // 4. three path-layer chains
  struct Chain { const float* base; const int* paths; const float* pw; int N; int L; float* fin; };
  Chain chains[3] = {
    { init,                paths_mm, pw1, Nm, L1, Fmm },
    { init + (size_t)Nm*D, paths_dd, pw1, Nd, L1, Fdd },
    { init,                paths_md, pw2, Nt, L2, Fmd },
  };
  constexpr int TR = 8;
  const int RB = 2 * TR;
  for (int ci = 0; ci < 3; ++ci) {
    Chain& ch = chains[ci];
    const float* cur = ch.base;
    for (int l = 0; l < layers; ++l) {
      const float* pwl = ch.pw + (size_t)l * ch.L * D;
      int ggrid = cdiv(ch.N, 2);
      if (ch.L == 4)      gather_einsum<4><<<ggrid, 256, 0, stream>>>(cur, ch.paths, pwl, bufR, ch.N, P);
      else if (ch.L == 6) gather_einsum<6><<<ggrid, 256, 0, stream>>>(cur, ch.paths, pwl, bufR, ch.N, P);
      else                gather_einsum_rt<<<ggrid, 256, 0, stream>>>(cur, ch.paths, pwl, bufR, ch.N, P, ch.L);
      float* dst = (l == layers - 1) ? ch.fin : bufA;
      fc_residual<TR><<<cdiv(ch.N, RB), 256, 0, stream>>>(bufR, fcW + (size_t)l * D * D, ch.base, dst, ch.N);
      cur = dst;
    }
  }

  // 5. per-node partial dots + scoring
  node_partial<<<cdiv(Nt * 64, 256), 256, 0, stream>>>(Fmm, Fdd, Fmd, w512, uv, Nm, Nt);
  score_kernel<<<cdiv(S, 256), 256, 0, stream>>>(samples, uv, uv + Nm, csc, out, S);
}

// Round 3
// 644.254 us; speedup vs baseline: 2.1889x; 1.0772x over previous
//
#include <hip/hip_runtime.h>
#include <hip/hip_bf16.h>
#include <cstdint>
#include <cstddef>

#define ALPHA_ 0.1f

static inline int cdiv(int a, int b) { return (a + b - 1) / b; }

typedef __attribute__((ext_vector_type(8))) short short8;
typedef __attribute__((ext_vector_type(4))) float float4v;

// ---------------- Wt builder: Wt[c][k] = bf16(W[k][c]), zero-padded to Kpad ----------------
__global__ __launch_bounds__(256) void make_wt(const float* __restrict__ W,
                                               __hip_bfloat16* __restrict__ Wt,
                                               int K, int Kpad)
{
  const int c = blockIdx.y;
  const int k = blockIdx.x * 256 + threadIdx.x;
  if (k >= Kpad) return;
  float v = (k < K) ? W[(size_t)k * 128 + c] : 0.f;
  Wt[(size_t)c * Kpad + k] = __float2bfloat16(v);
}

__device__ __forceinline__ void loadA8(const float* p, float* f)
{
  float4v t0 = *(const float4v*)p;
  float4v t1 = *(const float4v*)(p + 4);
  f[0]=t0.x; f[1]=t0.y; f[2]=t0.z; f[3]=t0.w;
  f[4]=t1.x; f[5]=t1.y; f[6]=t1.z; f[7]=t1.w;
}

__device__ __forceinline__ int clampS(int sp, int s_main) { return sp < s_main ? sp : s_main - 1; }

__device__ __forceinline__ void mfma_step(const float* f, const __hip_bfloat16* wk, int Kpad, float4v* acc)
{
  union { short8 v; __hip_bfloat16 h[8]; } bb;
#pragma unroll
  for (int j = 0; j < 8; ++j) bb.h[j] = __float2bfloat16(f[j]);
#pragma unroll
  for (int mt = 0; mt < 8; ++mt) {
    short8 a = *(const short8*)(wk + (size_t)mt * 16 * Kpad);
    acc[mt] = __builtin_amdgcn_mfma_f32_16x16x32_bf16(a, bb.v, acc[mt], 0, 0, 0);
  }
}

// ---------------- init GEMM via MFMA, software-pipelined, split-K=5 ----------------
// Wave: 16 rows x 128 cols. A rows are the MFMA B operand (f32->bf16 in-reg).
template<int KSPLIT>
__global__ __launch_bounds__(256, 4) void init_mfma(
    const float* __restrict__ Am, const __hip_bfloat16* __restrict__ Wtm, int Nm_, int nbm,
    const float* __restrict__ Ad, const __hip_bfloat16* __restrict__ Wtd, int Nd_, int Kpd,
    float* __restrict__ p0, float* __restrict__ p1, float* __restrict__ p2,
    float* __restrict__ p3, float* __restrict__ p4)
{
  const int lane = threadIdx.x & 63;
  const int wv   = threadIdx.x >> 6;
  const int nb_total = gridDim.x / KSPLIT;
  int mb    = blockIdx.x % nb_total;
  int chunk = blockIdx.x / nb_total;

  const float* A; const __hip_bfloat16* Wt; int N, K, Kpad, rowoff, rb;
  if (mb < nbm) { A = Am; Wt = Wtm; N = Nm_; K = Nm_; Kpad = Nm_; rowoff = 0;   rb = mb; }
  else          { A = Ad; Wt = Wtd; N = Nd_; K = Nd_; Kpad = Kpd; rowoff = Nm_; rb = mb - nbm; }

  float* Cp = (chunk == 0) ? p0 : (chunk == 1) ? p1 : (chunk == 2) ? p2 : (chunk == 3) ? p3 : p4;

  const int St = Kpad / 32;
  const int s0 = (int)(((long)St * chunk) / KSPLIT);
  const int s1 = (int)(((long)St * (chunk + 1)) / KSPLIT);

  const int row0 = rb * 64 + wv * 16;
  const int rloc = lane & 15;
  const int kg   = (lane >> 4) * 8;

  int r  = row0 + rloc;
  int ra = (r < N) ? r : (N - 1);
  const float* arow = A + (size_t)ra * K + kg;
  const __hip_bfloat16* wbase = Wt + (size_t)rloc * Kpad + kg;

  float4v acc[8];
#pragma unroll
  for (int mt = 0; mt < 8; ++mt) acc[mt] = (float4v){0.f, 0.f, 0.f, 0.f};

  const int s_full = K / 32;                       // steps with no tail guard
  const int s_main = (s1 < s_full) ? s1 : s_full;

  if (s_main > s0) {
    float f0[8], f1[8], f2[8], f3[8];
    loadA8(arow + (size_t)clampS(s0 + 0, s_main) * 32, f0);
    loadA8(arow + (size_t)clampS(s0 + 1, s_main) * 32, f1);
    loadA8(arow + (size_t)clampS(s0 + 2, s_main) * 32, f2);
    loadA8(arow + (size_t)clampS(s0 + 3, s_main) * 32, f3);
    int s = s0;
    for (; s + 4 <= s_main; s += 4) {
      mfma_step(f0, wbase + (size_t)(s + 0) * 32, Kpad, acc);
      loadA8(arow + (size_t)clampS(s + 4, s_main) * 32, f0);
      mfma_step(f1, wbase + (size_t)(s + 1) * 32, Kpad, acc);
      loadA8(arow + (size_t)clampS(s + 5, s_main) * 32, f1);
      mfma_step(f2, wbase + (size_t)(s + 2) * 32, Kpad, acc);
      loadA8(arow + (size_t)clampS(s + 6, s_main) * 32, f2);
      mfma_step(f3, wbase + (size_t)(s + 3) * 32, Kpad, acc);
      loadA8(arow + (size_t)clampS(s + 7, s_main) * 32, f3);
    }
    const int rem = s_main - s;
    if (rem > 0) mfma_step(f0, wbase + (size_t)(s + 0) * 32, Kpad, acc);
    if (rem > 1) mfma_step(f1, wbase + (size_t)(s + 1) * 32, Kpad, acc);
    if (rem > 2) mfma_step(f2, wbase + (size_t)(s + 2) * 32, Kpad, acc);
  }

  // guarded tail (only the last chunk of the 6000-K matrix hits this)
  for (int s = s_main; s < s1; ++s) {
    float f[8];
    const int kb = s * 32 + kg;
#pragma unroll
    for (int j = 0; j < 8; ++j) f[j] = (kb + j < K) ? arow[(size_t)s * 32 + j] : 0.f;
    mfma_step(f, wbase + (size_t)s * 32, Kpad, acc);
  }

  if (r < N) {
    float* dst = Cp + ((size_t)(rowoff + r)) * 128 + (lane >> 4) * 4;
#pragma unroll
    for (int mt = 0; mt < 8; ++mt)
      *(float4v*)(dst + mt * 16) = acc[mt];
  }
}

// sum 5 partials; write init AND both state copies (state sections alias b,c — reads precede writes per-thread)
__global__ __launch_bounds__(256) void combine5(
    const float4v* a, const float4v* b, const float4v* c, const float4v* d, const float4v* e,
    float4v* o_init, float4v* o_s0, float4v* o_s1, int n4)
{
  int i = blockIdx.x * 256 + threadIdx.x;
  if (i >= n4) return;
  float4v x = a[i], y = b[i], z = c[i], u = d[i], v = e[i];
  float4v s = (float4v){x.x+y.x+z.x+u.x+v.x, x.y+y.y+z.y+u.y+v.y,
                        x.z+y.z+z.z+u.z+v.z, x.w+y.w+z.w+u.w+v.w};
  o_init[i] = s; o_s0[i] = s; o_s1[i] = s;
}

// ---------------- unified gather over all three chains ----------------
template<int L>
__device__ __forceinline__ float gath(const float* __restrict__ sect, const int* __restrict__ paths,
                                      const float* __restrict__ pw, int n, int N, int P, int d)
{
  float pwv[L];
#pragma unroll
  for (int l = 0; l < L; ++l) pwv[l] = pw[l * 128 + d];
  float acc = 0.f;
  for (int p = 0; p < P; ++p) {
    const int* ip = paths + ((size_t)p * N + n) * L;   // wave-uniform -> scalar loads
    int idx[L];
#pragma unroll
    for (int l = 0; l < L; ++l) idx[l] = ip[l];
#pragma unroll
    for (int l = 0; l < L; ++l)
      acc = fmaf(pwv[l], sect[(size_t)idx[l] * 128 + d], acc);
  }
  return acc;
}

template<int LMM, int LMD>
__global__ __launch_bounds__(256) void gather_all(
    const float* __restrict__ state,
    const int* __restrict__ paths_mm, const int* __restrict__ paths_dd, const int* __restrict__ paths_md,
    const float* __restrict__ pw1l, const float* __restrict__ pw2l,
    float* __restrict__ r, int Nm, int Nd, int P)
{
  const int d = threadIdx.x & 127;
  const int nsub = threadIdx.x >> 7;
  const int g = blockIdx.x * 2 + nsub;
  const int Nt = Nm + Nd;
  if (g >= 2 * Nt) return;
  float acc; int Pinv_n = P;
  if (g < Nm)
    acc = gath<LMM>(state, paths_mm, pw1l, g, Nm, P, d);
  else if (g < Nt)
    acc = gath<LMM>(state + (size_t)Nm * 128, paths_dd, pw1l, g - Nm, Nd, P, d);
  else
    acc = gath<LMD>(state + (size_t)Nt * 128, paths_md, pw2l, g - Nt, Nt, P, d);
  r[(size_t)g * 128 + d] = acc * (1.0f / (float)Pinv_n);
}

// runtime-L fallback, writes into r section starting at node base
__global__ __launch_bounds__(256) void gather_einsum_rt(
    const float* __restrict__ feats, const int* __restrict__ paths,
    const float* __restrict__ pw, float* __restrict__ r, int N, int P, int L)
{
  const int d = threadIdx.x & 127;
  const int n = blockIdx.x * 2 + (threadIdx.x >> 7);
  if (n >= N) return;
  float acc = 0.f;
  for (int p = 0; p < P; ++p) {
    const int* ip = paths + ((size_t)p * N + n) * L;
    for (int l = 0; l < L; ++l)
      acc = fmaf(pw[l * 128 + d], feats[(size_t)ip[l] * 128 + d], acc);
  }
  r[(size_t)n * 128 + d] = acc * (1.0f / (float)P);
}

// ---------------- f32 GEMV core for the fc layers ----------------
template<int TR>
__device__ __forceinline__ void gemm_acc(const float* __restrict__ A, const float* __restrict__ W,
                                         int N, int K, int row0, int col, float* acc)
{
  const float* arow[TR];
#pragma unroll
  for (int r = 0; r < TR; ++r) {
    int rr = row0 + r; if (rr > N - 1) rr = N - 1;
    arow[r] = A + (size_t)rr * K;
  }
#pragma unroll
  for (int r = 0; r < TR; ++r) acc[r] = 0.f;

  for (int k = 0; k < K; k += 8) {
    float w[8];
#pragma unroll
    for (int kk = 0; kk < 8; ++kk) w[kk] = W[(size_t)(k + kk) * 128 + col];
#pragma unroll
    for (int r = 0; r < TR; ++r) {
      const float* ap = arow[r] + k;
#pragma unroll
      for (int kk = 0; kk < 8; ++kk) acc[r] = fmaf(ap[kk], w[kk], acc[r]);
    }
  }
}

// state[rr] = ALPHA*init[base(rr)] + (1-ALPHA)*relu(R[rr] @ fcW), rr in [0, 2*Nt)
template<int TR>
__global__ __launch_bounds__(256) void fc_all(
    const float* __restrict__ Rm, const float* __restrict__ W,
    const float* __restrict__ initb, float* __restrict__ state, int Ntot, int Nt)
{
  const int col = threadIdx.x & 127;
  const int rh  = __builtin_amdgcn_readfirstlane((int)(threadIdx.x >> 7));
  const int row0 = blockIdx.x * (2 * TR) + rh * TR;
  float acc[TR];
  gemm_acc<TR>(Rm, W, Ntot, 128, row0, col, acc);
#pragma unroll
  for (int r = 0; r < TR; ++r) {
    int rr = row0 + r;
    if (rr < Ntot) {
      int rbase = (rr < Nt) ? rr : rr - Nt;
      state[(size_t)rr * 128 + col] =
          ALPHA_ * initb[(size_t)rbase * 128 + col] + (1.f - ALPHA_) * fmaxf(acc[r], 0.f);
    }
  }
}

// MLP collapse
__global__ void collapse1(const float* __restrict__ W0, const float* __restrict__ b0,
                          const float* __restrict__ W1, const float* __restrict__ b1,
                          float* __restrict__ w01, float* __restrict__ b01,
                          int E, int K0, int H1)
{
  int row = blockIdx.x; int c = threadIdx.x;
  if (c >= H1) return;
  const float* src; float acc;
  if (row < E) { src = W0 + (size_t)row * K0; acc = 0.f; }
  else         { src = b0; acc = b1[c]; }
  for (int k = 0; k < K0; ++k) acc = fmaf(src[k], W1[(size_t)k * H1 + c], acc);
  if (row < E) w01[(size_t)row * H1 + c] = acc; else b01[c] = acc;
}

__global__ void collapse2(const float* __restrict__ w01, const float* __restrict__ b01,
                          const float* __restrict__ W2, const float* __restrict__ b2,
                          float* __restrict__ w512, float* __restrict__ csc,
                          int E, int H1)
{
  int i = blockIdx.x * blockDim.x + threadIdx.x;
  if (i < E) {
    float a = 0.f;
    for (int j = 0; j < H1; ++j) a = fmaf(w01[(size_t)i * H1 + j], W2[j], a);
    w512[i] = a;
  } else if (i == E) {
    float a = b2[0];
    for (int j = 0; j < H1; ++j) a = fmaf(b01[j], W2[j], a);
    csc[0] = a;
  }
}

__global__ __launch_bounds__(256) void node_partial(
    const float* __restrict__ Fmm, const float* __restrict__ Fdd, const float* __restrict__ Fmd,
    const float* __restrict__ w512, float* __restrict__ uv, int Nm, int Nt)
{
  int gid = blockIdx.x * blockDim.x + threadIdx.x;
  int wid = gid >> 6;
  int lane = threadIdx.x & 63;
  if (wid >= Nt) return;
  bool isM = wid < Nm;
  const float* X = isM ? (Fmm + (size_t)wid * 128) : (Fdd + (size_t)(wid - Nm) * 128);
  const float* Y = Fmd + (size_t)wid * 128;
  const float* w1 = w512 + (isM ? 0 : 256);
  const float* w2 = w1 + 128;
  float s = fmaf(X[lane], w1[lane], 0.f);
  s = fmaf(X[lane + 64], w1[lane + 64], s);
  s = fmaf(Y[lane], w2[lane], s);
  s = fmaf(Y[lane + 64], w2[lane + 64], s);
#pragma unroll
  for (int off = 32; off > 0; off >>= 1) s += __shfl_down(s, off);
  if (lane == 0) uv[wid] = s;
}

__global__ __launch_bounds__(256) void score_kernel(
    const int* __restrict__ samples, const float* __restrict__ u, const float* __restrict__ v,
    const float* __restrict__ csc, float* __restrict__ out, int S)
{
  int s = blockIdx.x * blockDim.x + threadIdx.x;
  if (s >= S) return;
  const int2 ij = ((const int2*)samples)[s];
  float x = u[ij.x] + v[ij.y] + csc[0];
  out[s] = 1.0f / (1.0f + expf(-x));
}

extern "C" void kernel_launch(void* const* d_in, const int* in_sizes, int n_in,
                              void* d_out, int out_size, void* d_ws, size_t ws_size,
                              hipStream_t stream)
{
  const int*   paths_mm = (const int*)d_in[0];
  const int*   paths_dd = (const int*)d_in[1];
  const int*   paths_md = (const int*)d_in[2];
  const float* miRNA    = (const float*)d_in[3];
  const float* disease  = (const float*)d_in[4];
  const int*   samples  = (const int*)d_in[5];
  const float* Wm  = (const float*)d_in[6];
  const float* Wd  = (const float*)d_in[7];
  const float* pw1 = (const float*)d_in[8];
  const float* pw2 = (const float*)d_in[9];
  const float* fcW = (const float*)d_in[10];
  const float* W0  = (const float*)d_in[11];
  const float* b0  = (const float*)d_in[12];
  const float* W1  = (const float*)d_in[13];
  const float* b1  = (const float*)d_in[14];
  const float* W2  = (const float*)d_in[15];
  const float* b2  = (const float*)d_in[16];

  const int D  = 128;
  const int Nm = in_sizes[6] / D;
  const int Nd = in_sizes[7] / D;
  const int Nt = Nm + Nd;
  const int S  = in_sizes[5] / 2;
  const int layers = in_sizes[10] / (D * D);
  const int L1 = in_sizes[8] / (layers * D);
  const int L2 = in_sizes[9] / (layers * D);
  const int P  = in_sizes[0] / (Nm * L1);
  const int E  = 4 * D;
  const int K0 = in_sizes[12];
  const int H1 = in_sizes[14];
  const int Kpd = cdiv(Nd, 32) * 32;   // 6016

  float* out = (float*)d_out;
  float* ws  = (float*)d_ws;
  size_t off = 0;
  float* init  = ws + off; off += (size_t)Nt * D;       // summed init feats (m;d)
  float* state = ws + off; off += (size_t)2 * Nt * D;   // [mm(Nm); dd(Nd); md(Nt)]
  float* bufR  = ws + off; off += (size_t)2 * Nt * D;   // gather output
  float* w01   = ws + off; off += (size_t)E * H1;
  float* b01   = ws + off; off += H1;
  float* w512  = ws + off; off += E;
  float* csc   = ws + off; off += 1;
  float* uv    = ws + off; off += Nt;
  __hip_bfloat16* Wtm = (__hip_bfloat16*)(ws + off); off += (size_t)D * Nm / 2;
  __hip_bfloat16* Wtd = (__hip_bfloat16*)(ws + off); off += (size_t)D * Kpd / 2;
  (void)ws_size; (void)n_in; (void)out_size;

  // 1. bf16 transposed weights (tiny; L2-resident)
  {
    dim3 g1(cdiv(Nm, 256), D);  make_wt<<<g1, 256, 0, stream>>>(Wm, Wtm, Nm, Nm);
    dim3 g2(cdiv(Kpd, 256), D); make_wt<<<g2, 256, 0, stream>>>(Wd, Wtd, Nd, Kpd);
  }

  // 2. MLP collapse (independent of features)
  collapse1<<<E + 1, 64, 0, stream>>>(W0, b0, W1, b1, w01, b01, E, K0, H1);
  collapse2<<<cdiv(E + 1, 256), 256, 0, stream>>>(w01, b01, W2, b2, w512, csc, E, H1);

  // 3. init GEMMs via pipelined MFMA, split-K=5 (partials alias state/bufR, dead here)
  {
    constexpr int KSPLIT = 5;
    int nbm = cdiv(Nm, 64), nbd = cdiv(Nd, 64);
    init_mfma<KSPLIT><<<(nbm + nbd) * KSPLIT, 256, 0, stream>>>(
        miRNA, Wtm, Nm, nbm, disease, Wtd, Nd, Kpd,
        init, state, state + (size_t)Nt * D, bufR, bufR + (size_t)Nt * D);
    int n4 = Nt * D / 4;
    combine5<<<cdiv(n4, 256), 256, 0, stream>>>(
        (const float4v*)init, (const float4v*)state, (const float4v*)(state + (size_t)Nt * D),
        (const float4v*)bufR, (const float4v*)(bufR + (size_t)Nt * D),
        (float4v*)init, (float4v*)state, (float4v*)(state + (size_t)Nt * D), n4);
  }

  // 4. fused path-layer chains: one gather + one fc over all 2*Nt rows per layer
  constexpr int TR = 8;
  for (int l = 0; l < layers; ++l) {
    const float* pw1l = pw1 + (size_t)l * L1 * D;
    const float* pw2l = pw2 + (size_t)l * L2 * D;
    if (L1 == 4 && L2 == 6) {
      gather_all<4, 6><<<Nt, 256, 0, stream>>>(
          state, paths_mm, paths_dd, paths_md, pw1l, pw2l, bufR, Nm, Nd, P);
    } else {
      gather_einsum_rt<<<cdiv(Nm, 2), 256, 0, stream>>>(state, paths_mm, pw1l, bufR, Nm, P, L1);
      gather_einsum_rt<<<cdiv(Nd, 2), 256, 0, stream>>>(state + (size_t)Nm * D, paths_dd, pw1l,
                                                        bufR + (size_t)Nm * D, Nd, P, L1);
      gather_einsum_rt<<<cdiv(Nt, 2), 256, 0, stream>>>(state + (size_t)Nt * D, paths_md, pw2l,
                                                        bufR + (size_t)Nt * D, Nt, P, L2);
    }
    fc_all<TR><<<cdiv(2 * Nt, 2 * TR), 256, 0, stream>>>(
        bufR, fcW + (size_t)l * D * D, init, state, 2 * Nt, Nt);
  }

  // 5. per-node partial dots + scoring
  node_partial<<<cdiv(Nt * 64, 256), 256, 0, stream>>>(
      state, state + (size_t)Nm * D, state + (size_t)Nt * D, w512, uv, Nm, Nt);
  score_kernel<<<cdiv(S, 256), 256, 0, stream>>>(samples, uv, uv + Nm, csc, out, S);
}

// Round 4
// 419.140 us; speedup vs baseline: 3.3646x; 1.5371x over previous
//
#include <hip/hip_runtime.h>
#include <hip/hip_bf16.h>
#include <cstdint>
#include <cstddef>

#define ALPHA_ 0.1f

static inline int cdiv(int a, int b) { return (a + b - 1) / b; }

typedef __attribute__((ext_vector_type(8))) short short8;
typedef __attribute__((ext_vector_type(4))) short short4v;
typedef __attribute__((ext_vector_type(4))) float float4v;

// ---------------- Wt builder: Wt[c][k] = bf16(W[k][c]), zero-padded to Kpad ----------------
__global__ __launch_bounds__(256) void make_wt(const float* __restrict__ W,
                                               __hip_bfloat16* __restrict__ Wt,
                                               int K, int Kpad)
{
  const int c = blockIdx.y;
  const int k = blockIdx.x * 256 + threadIdx.x;
  if (k >= Kpad) return;
  float v = (k < K) ? W[(size_t)k * 128 + c] : 0.f;
  Wt[(size_t)c * Kpad + k] = __float2bfloat16(v);
}

// ---------------- init GEMM: LDS-staged, double-buffered, T2-swizzled MFMA ----------------
// Block: 256 thr = 4 waves; out tile 64 rows x 128 cols; BK=64; split-K=KSPLIT.
// LDS A: [64 rows][8 chunks of 8 bf16], chunk index XOR (row&7). Same for W [128 cols][8 chunks].
template<int KSPLIT>
__global__ __launch_bounds__(256, 3) void init_mfma_lds(
    const float* __restrict__ Am, const __hip_bfloat16* __restrict__ Wtm, int Nm_, int nbm,
    const float* __restrict__ Ad, const __hip_bfloat16* __restrict__ Wtd, int Nd_, int Kpd,
    float* __restrict__ p0, float* __restrict__ p1, float* __restrict__ p2,
    float* __restrict__ p3, float* __restrict__ p4)
{
  __shared__ __hip_bfloat16 lds_a[2][64 * 64];    // 16 KB
  __shared__ __hip_bfloat16 lds_w[2][128 * 64];   // 32 KB

  const int t    = threadIdx.x;
  const int lane = t & 63;
  const int wv   = t >> 6;

  const int nb_total = gridDim.x / KSPLIT;
  int mb    = blockIdx.x % nb_total;
  int chunk = blockIdx.x / nb_total;

  const float* A; const __hip_bfloat16* Wt; int N, K, Kpad, rowoff, rb;
  if (mb < nbm) { A = Am; Wt = Wtm; N = Nm_; K = Nm_; Kpad = Nm_; rowoff = 0;   rb = mb; }
  else          { A = Ad; Wt = Wtd; N = Nd_; K = Nd_; Kpad = Kpd; rowoff = Nm_; rb = mb - nbm; }

  float* Cp = (chunk == 0) ? p0 : (chunk == 1) ? p1 : (chunk == 2) ? p2 : (chunk == 3) ? p3 : p4;

  const int St = Kpad / 64;
  const int s0 = (int)(((long)St * chunk) / KSPLIT);
  const int s1 = (int)(((long)St * (chunk + 1)) / KSPLIT);

  // ---- A staging map: instr i stages row (wv*16 + i*4 + (lane>>4)), k-floats (lane&15)*4 ----
  const int st_arow = wv * 16 + (lane >> 4);          // + i*4
  const int st_akf  = (lane & 15) * 4;
  const int row_g0  = rb * 64;
  const float* arow_p[4];
#pragma unroll
  for (int i = 0; i < 4; ++i) {
    int rg = row_g0 + st_arow + i * 4;
    if (rg > N - 1) rg = N - 1;
    arow_p[i] = A + (size_t)rg * K;
  }
  // A LDS write offsets (elem units), fixed per thread per i
  const int a_jj  = (lane & 15) >> 1;
  const int a_sub = lane & 1;
  int a_woff[4];
#pragma unroll
  for (int i = 0; i < 4; ++i) {
    int r = st_arow + i * 4;
    a_woff[i] = r * 64 + ((a_jj ^ (r & 7)) << 3) + a_sub * 4;
  }

  // ---- W staging map: instr i stages 16B unit u = i*256 + t -> col=u>>3, j=u&7 ----
  const __hip_bfloat16* wsrc_p[4];
  int w_woff[4];
#pragma unroll
  for (int i = 0; i < 4; ++i) {
    int u = i * 256 + t;
    int col = u >> 3, j = u & 7;
    wsrc_p[i] = Wt + (size_t)col * Kpad + ((j ^ (col & 7)) << 3);  // + k0 per step
    w_woff[i] = u * 8;
  }

  // ---- compute-frag offsets (elem units), fixed except buffer ----
  const int rloc = lane & 15;
  const int kgj  = lane >> 4;            // j offset = kg/8
  const int r_a  = wv * 16 + rloc;
  int a_roff[2], w_roff[2][8];
#pragma unroll
  for (int h = 0; h < 2; ++h) {
    int j = h * 4 + kgj;
    a_roff[h] = r_a * 64 + ((j ^ (r_a & 7)) << 3);
#pragma unroll
    for (int mt = 0; mt < 8; ++mt) {
      int col = mt * 16 + rloc;
      w_roff[h][mt] = col * 64 + ((j ^ (col & 7)) << 3);
    }
  }

  float4v acc[8];
#pragma unroll
  for (int mt = 0; mt < 8; ++mt) acc[mt] = (float4v){0.f, 0.f, 0.f, 0.f};

  float4v a_st0, a_st1, a_st2, a_st3;
  short8  w_st0, w_st1, w_st2, w_st3;

#define STAGE_LOAD(s_)                                                          \
  {                                                                             \
    int kf = (s_) * 64 + st_akf; if (kf > K - 4) kf = K - 4;                    \
    const int k0 = (s_) * 64;                                                   \
    a_st0 = *(const float4v*)(arow_p[0] + kf);                                  \
    a_st1 = *(const float4v*)(arow_p[1] + kf);                                  \
    a_st2 = *(const float4v*)(arow_p[2] + kf);                                  \
    a_st3 = *(const float4v*)(arow_p[3] + kf);                                  \
    w_st0 = *(const short8*)(wsrc_p[0] + k0);                                   \
    w_st1 = *(const short8*)(wsrc_p[1] + k0);                                   \
    w_st2 = *(const short8*)(wsrc_p[2] + k0);                                   \
    w_st3 = *(const short8*)(wsrc_p[3] + k0);                                   \
  }

#define CVT4(dst_, src_)                                                        \
  { union { short4v v; __hip_bfloat16 h[4]; } c_;                               \
    c_.h[0] = __float2bfloat16(src_.x); c_.h[1] = __float2bfloat16(src_.y);     \
    c_.h[2] = __float2bfloat16(src_.z); c_.h[3] = __float2bfloat16(src_.w);     \
    dst_ = c_.v; }

#define STAGE_STORE(bb_)                                                        \
  {                                                                             \
    short4v c0, c1, c2, c3;                                                     \
    CVT4(c0, a_st0) CVT4(c1, a_st1) CVT4(c2, a_st2) CVT4(c3, a_st3)             \
    *(short4v*)(&lds_a[bb_][a_woff[0]]) = c0;                                   \
    *(short4v*)(&lds_a[bb_][a_woff[1]]) = c1;                                   \
    *(short4v*)(&lds_a[bb_][a_woff[2]]) = c2;                                   \
    *(short4v*)(&lds_a[bb_][a_woff[3]]) = c3;                                   \
    *(short8*)(&lds_w[bb_][w_woff[0]]) = w_st0;                                 \
    *(short8*)(&lds_w[bb_][w_woff[1]]) = w_st1;                                 \
    *(short8*)(&lds_w[bb_][w_woff[2]]) = w_st2;                                 \
    *(short8*)(&lds_w[bb_][w_woff[3]]) = w_st3;                                 \
  }

  // prologue
  STAGE_LOAD(s0);
  STAGE_STORE(0);
  __syncthreads();

  int bb = 0;
  for (int s = s0; s < s1; ++s) {
    const bool more = (s + 1 < s1);
    if (more) STAGE_LOAD(s + 1);

    const __hip_bfloat16* la = lds_a[bb];
    const __hip_bfloat16* lw = lds_w[bb];
#pragma unroll
    for (int h = 0; h < 2; ++h) {
      short8 afrag = *(const short8*)(la + a_roff[h]);
#pragma unroll
      for (int mt = 0; mt < 8; ++mt) {
        short8 wfrag = *(const short8*)(lw + w_roff[h][mt]);
        acc[mt] = __builtin_amdgcn_mfma_f32_16x16x32_bf16(wfrag, afrag, acc[mt], 0, 0, 0);
      }
    }

    if (more) STAGE_STORE(bb ^ 1);
    __syncthreads();
    bb ^= 1;
  }

  int r = row_g0 + r_a;
  if (r < N) {
    float* dst = Cp + ((size_t)(rowoff + r)) * 128 + (lane >> 4) * 4;
#pragma unroll
    for (int mt = 0; mt < 8; ++mt)
      *(float4v*)(dst + mt * 16) = acc[mt];
  }
#undef STAGE_LOAD
#undef CVT4
#undef STAGE_STORE
}

// sum 5 partials; write init AND both state copies (aliasing OK: per-thread read-then-write)
__global__ __launch_bounds__(256) void combine5(
    const float4v* a, const float4v* b, const float4v* c, const float4v* d, const float4v* e,
    float4v* o_init, float4v* o_s0, float4v* o_s1, int n4)
{
  int i = blockIdx.x * 256 + threadIdx.x;
  if (i >= n4) return;
  float4v x = a[i], y = b[i], z = c[i], u = d[i], v = e[i];
  float4v s = (float4v){x.x+y.x+z.x+u.x+v.x, x.y+y.y+z.y+u.y+v.y,
                        x.z+y.z+z.z+u.z+v.z, x.w+y.w+z.w+u.w+v.w};
  o_init[i] = s; o_s0[i] = s; o_s1[i] = s;
}

// ---------------- unified gather over all three chains ----------------
template<int L>
__device__ __forceinline__ float gath(const float* __restrict__ sect, const int* __restrict__ paths,
                                      const float* __restrict__ pw, int n, int N, int P, int d)
{
  float pwv[L];
#pragma unroll
  for (int l = 0; l < L; ++l) pwv[l] = pw[l * 128 + d];
  float acc = 0.f;
  for (int p = 0; p < P; ++p) {
    const int* ip = paths + ((size_t)p * N + n) * L;   // wave-uniform -> scalar loads
    int idx[L];
#pragma unroll
    for (int l = 0; l < L; ++l) idx[l] = ip[l];
#pragma unroll
    for (int l = 0; l < L; ++l)
      acc = fmaf(pwv[l], sect[(size_t)idx[l] * 128 + d], acc);
  }
  return acc;
}

template<int LMM, int LMD>
__global__ __launch_bounds__(256) void gather_all(
    const float* __restrict__ state,
    const int* __restrict__ paths_mm, const int* __restrict__ paths_dd, const int* __restrict__ paths_md,
    const float* __restrict__ pw1l, const float* __restrict__ pw2l,
    float* __restrict__ r, int Nm, int Nd, int P)
{
  const int d = threadIdx.x & 127;
  const int nsub = threadIdx.x >> 7;
  const int g = blockIdx.x * 2 + nsub;
  const int Nt = Nm + Nd;
  if (g >= 2 * Nt) return;
  float acc;
  if (g < Nm)
    acc = gath<LMM>(state, paths_mm, pw1l, g, Nm, P, d);
  else if (g < Nt)
    acc = gath<LMM>(state + (size_t)Nm * 128, paths_dd, pw1l, g - Nm, Nd, P, d);
  else
    acc = gath<LMD>(state + (size_t)Nt * 128, paths_md, pw2l, g - Nt, Nt, P, d);
  r[(size_t)g * 128 + d] = acc * (1.0f / (float)P);
}

// runtime-L fallback
__global__ __launch_bounds__(256) void gather_einsum_rt(
    const float* __restrict__ feats, const int* __restrict__ paths,
    const float* __restrict__ pw, float* __restrict__ r, int N, int P, int L)
{
  const int d = threadIdx.x & 127;
  const int n = blockIdx.x * 2 + (threadIdx.x >> 7);
  if (n >= N) return;
  float acc = 0.f;
  for (int p = 0; p < P; ++p) {
    const int* ip = paths + ((size_t)p * N + n) * L;
    for (int l = 0; l < L; ++l)
      acc = fmaf(pw[l * 128 + d], feats[(size_t)ip[l] * 128 + d], acc);
  }
  r[(size_t)n * 128 + d] = acc * (1.0f / (float)P);
}

// ---------------- f32 GEMV core for the fc layers ----------------
template<int TR>
__device__ __forceinline__ void gemm_acc(const float* __restrict__ A, const float* __restrict__ W,
                                         int N, int K, int row0, int col, float* acc)
{
  const float* arow[TR];
#pragma unroll
  for (int r = 0; r < TR; ++r) {
    int rr = row0 + r; if (rr > N - 1) rr = N - 1;
    arow[r] = A + (size_t)rr * K;
  }
#pragma unroll
  for (int r = 0; r < TR; ++r) acc[r] = 0.f;

  for (int k = 0; k < K; k += 8) {
    float w[8];
#pragma unroll
    for (int kk = 0; kk < 8; ++kk) w[kk] = W[(size_t)(k + kk) * 128 + col];
#pragma unroll
    for (int r = 0; r < TR; ++r) {
      const float* ap = arow[r] + k;
#pragma unroll
      for (int kk = 0; kk < 8; ++kk) acc[r] = fmaf(ap[kk], w[kk], acc[r]);
    }
  }
}

// state[rr] = ALPHA*init[base(rr)] + (1-ALPHA)*relu(R[rr] @ fcW), rr in [0, 2*Nt)
template<int TR>
__global__ __launch_bounds__(256) void fc_all(
    const float* __restrict__ Rm, const float* __restrict__ W,
    const float* __restrict__ initb, float* __restrict__ state, int Ntot, int Nt)
{
  const int col = threadIdx.x & 127;
  const int rh  = __builtin_amdgcn_readfirstlane((int)(threadIdx.x >> 7));
  const int row0 = blockIdx.x * (2 * TR) + rh * TR;
  float acc[TR];
  gemm_acc<TR>(Rm, W, Ntot, 128, row0, col, acc);
#pragma unroll
  for (int r = 0; r < TR; ++r) {
    int rr = row0 + r;
    if (rr < Ntot) {
      int rbase = (rr < Nt) ? rr : rr - Nt;
      state[(size_t)rr * 128 + col] =
          ALPHA_ * initb[(size_t)rbase * 128 + col] + (1.f - ALPHA_) * fmaxf(acc[r], 0.f);
    }
  }
}

// MLP collapse
__global__ void collapse1(const float* __restrict__ W0, const float* __restrict__ b0,
                          const float* __restrict__ W1, const float* __restrict__ b1,
                          float* __restrict__ w01, float* __restrict__ b01,
                          int E, int K0, int H1)
{
  int row = blockIdx.x; int c = threadIdx.x;
  if (c >= H1) return;
  const float* src; float acc;
  if (row < E) { src = W0 + (size_t)row * K0; acc = 0.f; }
  else         { src = b0; acc = b1[c]; }
  for (int k = 0; k < K0; ++k) acc = fmaf(src[k], W1[(size_t)k * H1 + c], acc);
  if (row < E) w01[(size_t)row * H1 + c] = acc; else b01[c] = acc;
}

__global__ void collapse2(const float* __restrict__ w01, const float* __restrict__ b01,
                          const float* __restrict__ W2, const float* __restrict__ b2,
                          float* __restrict__ w512, float* __restrict__ csc,
                          int E, int H1)
{
  int i = blockIdx.x * blockDim.x + threadIdx.x;
  if (i < E) {
    float a = 0.f;
    for (int j = 0; j < H1; ++j) a = fmaf(w01[(size_t)i * H1 + j], W2[j], a);
    w512[i] = a;
  } else if (i == E) {
    float a = b2[0];
    for (int j = 0; j < H1; ++j) a = fmaf(b01[j], W2[j], a);
    csc[0] = a;
  }
}

__global__ __launch_bounds__(256) void node_partial(
    const float* __restrict__ Fmm, const float* __restrict__ Fdd, const float* __restrict__ Fmd,
    const float* __restrict__ w512, float* __restrict__ uv, int Nm, int Nt)
{
  int gid = blockIdx.x * blockDim.x + threadIdx.x;
  int wid = gid >> 6;
  int lane = threadIdx.x & 63;
  if (wid >= Nt) return;
  bool isM = wid < Nm;
  const float* X = isM ? (Fmm + (size_t)wid * 128) : (Fdd + (size_t)(wid - Nm) * 128);
  const float* Y = Fmd + (size_t)wid * 128;
  const float* w1 = w512 + (isM ? 0 : 256);
  const float* w2 = w1 + 128;
  float s = fmaf(X[lane], w1[lane], 0.f);
  s = fmaf(X[lane + 64], w1[lane + 64], s);
  s = fmaf(Y[lane], w2[lane], s);
  s = fmaf(Y[lane + 64], w2[lane + 64], s);
#pragma unroll
  for (int off = 32; off > 0; off >>= 1) s += __shfl_down(s, off);
  if (lane == 0) uv[wid] = s;
}

__global__ __launch_bounds__(256) void score_kernel(
    const int* __restrict__ samples, const float* __restrict__ u, const float* __restrict__ v,
    const float* __restrict__ csc, float* __restrict__ out, int S)
{
  int s = blockIdx.x * blockDim.x + threadIdx.x;
  if (s >= S) return;
  const int2 ij = ((const int2*)samples)[s];
  float x = u[ij.x] + v[ij.y] + csc[0];
  out[s] = 1.0f / (1.0f + expf(-x));
}

extern "C" void kernel_launch(void* const* d_in, const int* in_sizes, int n_in,
                              void* d_out, int out_size, void* d_ws, size_t ws_size,
                              hipStream_t stream)
{
  const int*   paths_mm = (const int*)d_in[0];
  const int*   paths_dd = (const int*)d_in[1];
  const int*   paths_md = (const int*)d_in[2];
  const float* miRNA    = (const float*)d_in[3];
  const float* disease  = (const float*)d_in[4];
  const int*   samples  = (const int*)d_in[5];
  const float* Wm  = (const float*)d_in[6];
  const float* Wd  = (const float*)d_in[7];
  const float* pw1 = (const float*)d_in[8];
  const float* pw2 = (const float*)d_in[9];
  const float* fcW = (const float*)d_in[10];
  const float* W0  = (const float*)d_in[11];
  const float* b0  = (const float*)d_in[12];
  const float* W1  = (const float*)d_in[13];
  const float* b1  = (const float*)d_in[14];
  const float* W2  = (const float*)d_in[15];
  const float* b2  = (const float*)d_in[16];

  const int D  = 128;
  const int Nm = in_sizes[6] / D;
  const int Nd = in_sizes[7] / D;
  const int Nt = Nm + Nd;
  const int S  = in_sizes[5] / 2;
  const int layers = in_sizes[10] / (D * D);
  const int L1 = in_sizes[8] / (layers * D);
  const int L2 = in_sizes[9] / (layers * D);
  const int P  = in_sizes[0] / (Nm * L1);
  const int E  = 4 * D;
  const int K0 = in_sizes[12];
  const int H1 = in_sizes[14];
  const int Kpm = cdiv(Nm, 64) * 64;   // 8000
  const int Kpd = cdiv(Nd, 64) * 64;   // 6016

  float* out = (float*)d_out;
  float* ws  = (float*)d_ws;
  size_t off = 0;
  float* init  = ws + off; off += (size_t)Nt * D;       // summed init feats (m;d)
  float* state = ws + off; off += (size_t)2 * Nt * D;   // [mm(Nm); dd(Nd); md(Nt)]
  float* bufR  = ws + off; off += (size_t)2 * Nt * D;   // gather output
  float* w01   = ws + off; off += (size_t)E * H1;
  float* b01   = ws + off; off += H1;
  float* w512  = ws + off; off += E;
  float* csc   = ws + off; off += 1;
  float* uv    = ws + off; off += Nt;
  __hip_bfloat16* Wtm = (__hip_bfloat16*)(ws + off); off += (size_t)D * Kpm / 2;
  __hip_bfloat16* Wtd = (__hip_bfloat16*)(ws + off); off += (size_t)D * Kpd / 2;
  (void)ws_size; (void)n_in; (void)out_size;

  // 1. bf16 transposed weights (tiny; L2-resident)
  {
    dim3 g1(cdiv(Kpm, 256), D); make_wt<<<g1, 256, 0, stream>>>(Wm, Wtm, Nm, Kpm);
    dim3 g2(cdiv(Kpd, 256), D); make_wt<<<g2, 256, 0, stream>>>(Wd, Wtd, Nd, Kpd);
  }

  // 2. MLP collapse (independent of features)
  collapse1<<<E + 1, 64, 0, stream>>>(W0, b0, W1, b1, w01, b01, E, K0, H1);
  collapse2<<<cdiv(E + 1, 256), 256, 0, stream>>>(w01, b01, W2, b2, w512, csc, E, H1);

  // 3. init GEMMs via LDS-staged MFMA, split-K=5 (partials alias state/bufR, dead here)
  {
    constexpr int KSPLIT = 5;
    int nbm = cdiv(Nm, 64), nbd = cdiv(Nd, 64);
    init_mfma_lds<KSPLIT><<<(nbm + nbd) * KSPLIT, 256, 0, stream>>>(
        miRNA, Wtm, Nm, nbm, disease, Wtd, Nd, Kpd,
        init, state, state + (size_t)Nt * D, bufR, bufR + (size_t)Nt * D);
    int n4 = Nt * D / 4;
    combine5<<<cdiv(n4, 256), 256, 0, stream>>>(
        (const float4v*)init, (const float4v*)state, (const float4v*)(state + (size_t)Nt * D),
        (const float4v*)bufR, (const float4v*)(bufR + (size_t)Nt * D),
        (float4v*)init, (float4v*)state, (float4v*)(state + (size_t)Nt * D), n4);
  }

  // 4. fused path-layer chains: one gather + one fc over all 2*Nt rows per layer
  constexpr int TR = 8;
  for (int l = 0; l < layers; ++l) {
    const float* pw1l = pw1 + (size_t)l * L1 * D;
    const float* pw2l = pw2 + (size_t)l * L2 * D;
    if (L1 == 4 && L2 == 6) {
      gather_all<4, 6><<<Nt, 256, 0, stream>>>(
          state, paths_mm, paths_dd, paths_md, pw1l, pw2l, bufR, Nm, Nd, P);
    } else {
      gather_einsum_rt<<<cdiv(Nm, 2), 256, 0, stream>>>(state, paths_mm, pw1l, bufR, Nm, P, L1);
      gather_einsum_rt<<<cdiv(Nd, 2), 256, 0, stream>>>(state + (size_t)Nm * D, paths_dd, pw1l,
                                                        bufR + (size_t)Nm * D, Nd, P, L1);
      gather_einsum_rt<<<cdiv(Nt, 2), 256, 0, stream>>>(state + (size_t)Nt * D, paths_md, pw2l,
                                                        bufR + (size_t)Nt * D, Nt, P, L2);
    }
    fc_all<TR><<<cdiv(2 * Nt, 2 * TR), 256, 0, stream>>>(
        bufR, fcW + (size_t)l * D * D, init, state, 2 * Nt, Nt);
  }

  // 5. per-node partial dots + scoring
  node_partial<<<cdiv(Nt * 64, 256), 256, 0, stream>>>(
      state, state + (size_t)Nm * D, state + (size_t)Nt * D, w512, uv, Nm, Nt);
  score_kernel<<<cdiv(S, 256), 256, 0, stream>>>(samples, uv, uv + Nm, csc, out, S);
}

// Round 5
// 358.247 us; speedup vs baseline: 3.9365x; 1.1700x over previous
//
#include <hip/hip_runtime.h>
#include <hip/hip_bf16.h>
#include <cstdint>
#include <cstddef>

#define ALPHA_ 0.1f

static inline int cdiv(int a, int b) { return (a + b - 1) / b; }

typedef __attribute__((ext_vector_type(8))) short short8;
typedef __attribute__((ext_vector_type(4))) short short4v;
typedef __attribute__((ext_vector_type(4))) float float4v;

__device__ __forceinline__ void gload_lds16(const void* g, void* l) {
  __builtin_amdgcn_global_load_lds((const __attribute__((address_space(1))) unsigned int*)g,
                                   (__attribute__((address_space(3))) unsigned int*)l,
                                   16, 0, 0);
}

// ---------------- WtT builder: tiled + swizzled bf16 transpose of W (K x 128) ----------------
// Tile s covers k in [s*64,(s+1)*64). Element (k,c) stored at
//   s*8192 + c*64 + ((j ^ (c&7))<<3) + e   where j=(k>>3)&7, e=k&7.
// This is exactly the per-step LDS image, so init can DMA it linearly.
__global__ __launch_bounds__(256) void make_wtT(const float* __restrict__ W,
                                                __hip_bfloat16* __restrict__ WtT,
                                                int K)
{
  __shared__ float tile[64][33];
  const int t  = threadIdx.x;
  const int k0 = blockIdx.x * 64;
  const int c0 = blockIdx.y * 32;
  {
    const int cc = t & 31;
    const int kr = t >> 5;              // 0..7
#pragma unroll
    for (int pass = 0; pass < 8; ++pass) {
      int k = k0 + kr + pass * 8;
      float v = (k < K) ? W[(size_t)k * 128 + (c0 + cc)] : 0.f;
      tile[kr + pass * 8][cc] = v;
    }
  }
  __syncthreads();
  {
    const int kk = t & 63;
    const int cl = t >> 6;              // 0..3
    const int s  = k0 >> 6;
    const int j  = kk >> 3, e = kk & 7;
#pragma unroll
    for (int pass = 0; pass < 8; ++pass) {
      int c = c0 + cl + pass * 4;
      size_t addr = (size_t)s * 8192 + (size_t)c * 64 + (size_t)(((j ^ (c & 7)) << 3) + e);
      WtT[addr] = __float2bfloat16(tile[kk][cl + pass * 4]);
    }
  }
}

// ---------------- init GEMM: 128x128 tile, 8 waves, LDS dbuf, W via global_load_lds ----------
template<int KSPLIT>
__global__ __launch_bounds__(512, 4) void init_mfma_lds(
    const float* __restrict__ Am, const __hip_bfloat16* __restrict__ Wtm, int Nm_, int nbm,
    const float* __restrict__ Ad, const __hip_bfloat16* __restrict__ Wtd, int Nd_, int Kpd,
    float* __restrict__ p0, float* __restrict__ p1, float* __restrict__ p2,
    float* __restrict__ p3, float* __restrict__ p4)
{
  __shared__ __hip_bfloat16 lds_a[2][128 * 64];   // 32 KB
  __shared__ __hip_bfloat16 lds_w[2][128 * 64];   // 32 KB

  const int t    = threadIdx.x;
  const int lane = t & 63;
  const int wv   = t >> 6;

  const int nb_total = gridDim.x / KSPLIT;
  int mb    = blockIdx.x % nb_total;
  int chunk = blockIdx.x / nb_total;

  const float* A; const __hip_bfloat16* Wt; int N, K, Kpad, rowoff, rb;
  if (mb < nbm) { A = Am; Wt = Wtm; N = Nm_; K = Nm_; Kpad = Nm_; rowoff = 0;   rb = mb; }
  else          { A = Ad; Wt = Wtd; N = Nd_; K = Nd_; Kpad = Kpd; rowoff = Nm_; rb = mb - nbm; }

  float* Cp = (chunk == 0) ? p0 : (chunk == 1) ? p1 : (chunk == 2) ? p2 : (chunk == 3) ? p3 : p4;

  const int St = Kpad / 64;
  const int s0 = (int)(((long)St * chunk) / KSPLIT);
  const int s1 = (int)(((long)St * (chunk + 1)) / KSPLIT);

  // A staging: wave wv stages rows wv*16 + (lane>>4) + i*4 (i<4), k-floats (lane&15)*4
  const int st_arow = wv * 16 + (lane >> 4);
  const int st_akf  = (lane & 15) * 4;
  const int row_g0  = rb * 128;
  const float* arow_p[4];
#pragma unroll
  for (int i = 0; i < 4; ++i) {
    int rg = row_g0 + st_arow + i * 4;
    if (rg > N - 1) rg = N - 1;
    arow_p[i] = A + (size_t)rg * K;
  }
  const int a_jj  = (lane & 15) >> 1;
  const int a_sub = lane & 1;
  int a_woff[4];
#pragma unroll
  for (int i = 0; i < 4; ++i) {
    int r = st_arow + i * 4;
    a_woff[i] = r * 64 + ((a_jj ^ (r & 7)) << 3) + a_sub * 4;
  }

  // compute-frag offsets
  const int rloc = lane & 15;
  const int kgj  = lane >> 4;
  const int r_a  = wv * 16 + rloc;
  int a_roff[2], w_roff[2][8];
#pragma unroll
  for (int h = 0; h < 2; ++h) {
    int j = h * 4 + kgj;
    a_roff[h] = r_a * 64 + ((j ^ (r_a & 7)) << 3);
#pragma unroll
    for (int mt = 0; mt < 8; ++mt) {
      int col = mt * 16 + rloc;
      w_roff[h][mt] = col * 64 + ((j ^ (col & 7)) << 3);
    }
  }

  float4v acc[8];
#pragma unroll
  for (int mt = 0; mt < 8; ++mt) acc[mt] = (float4v){0.f, 0.f, 0.f, 0.f};

  float4v a_st0, a_st1, a_st2, a_st3;
  const char* wt_bytes = (const char*)Wt;

#define STAGE_LOAD(s_, bb_)                                                       \
  {                                                                               \
    int kf = (s_) * 64 + st_akf; if (kf > K - 4) kf = K - 4;                      \
    a_st0 = *(const float4v*)(arow_p[0] + kf);                                    \
    a_st1 = *(const float4v*)(arow_p[1] + kf);                                    \
    a_st2 = *(const float4v*)(arow_p[2] + kf);                                    \
    a_st3 = *(const float4v*)(arow_p[3] + kf);                                    \
    const char* gs_ = wt_bytes + (size_t)(s_) * 16384;                            \
    gload_lds16(gs_ + (size_t)(wv * 64 + lane) * 16,                              \
                &lds_w[bb_][(size_t)(wv * 64) * 8]);                              \
    gload_lds16(gs_ + (size_t)(512 + wv * 64 + lane) * 16,                        \
                &lds_w[bb_][(size_t)(512 + wv * 64) * 8]);                        \
  }

#define CVT4(dst_, src_)                                                          \
  { union { short4v v; __hip_bfloat16 h[4]; } c_;                                 \
    c_.h[0] = __float2bfloat16(src_.x); c_.h[1] = __float2bfloat16(src_.y);       \
    c_.h[2] = __float2bfloat16(src_.z); c_.h[3] = __float2bfloat16(src_.w);       \
    dst_ = c_.v; }

#define STAGE_STORE(bb_)                                                          \
  {                                                                               \
    short4v c0, c1, c2, c3;                                                       \
    CVT4(c0, a_st0) CVT4(c1, a_st1) CVT4(c2, a_st2) CVT4(c3, a_st3)               \
    *(short4v*)(&lds_a[bb_][a_woff[0]]) = c0;                                     \
    *(short4v*)(&lds_a[bb_][a_woff[1]]) = c1;                                     \
    *(short4v*)(&lds_a[bb_][a_woff[2]]) = c2;                                     \
    *(short4v*)(&lds_a[bb_][a_woff[3]]) = c3;                                     \
  }

  STAGE_LOAD(s0, 0);
  STAGE_STORE(0);
  __syncthreads();

  int bb = 0;
  for (int s = s0; s < s1; ++s) {
    const bool more = (s + 1 < s1);
    if (more) STAGE_LOAD(s + 1, bb ^ 1);

    const __hip_bfloat16* la = lds_a[bb];
    const __hip_bfloat16* lw = lds_w[bb];
#pragma unroll
    for (int h = 0; h < 2; ++h) {
      short8 afrag = *(const short8*)(la + a_roff[h]);
#pragma unroll
      for (int mt = 0; mt < 8; ++mt) {
        short8 wfrag = *(const short8*)(lw + w_roff[h][mt]);
        acc[mt] = __builtin_amdgcn_mfma_f32_16x16x32_bf16(wfrag, afrag, acc[mt], 0, 0, 0);
      }
    }

    if (more) STAGE_STORE(bb ^ 1);
    __syncthreads();
    bb ^= 1;
  }

  int r = row_g0 + r_a;
  if (r < N) {
    float* dst = Cp + (size_t)(rowoff + r) * 128 + (lane >> 4) * 4;
#pragma unroll
    for (int mt = 0; mt < 8; ++mt)
      *(float4v*)(dst + mt * 16) = acc[mt];
  }
#undef STAGE_LOAD
#undef CVT4
#undef STAGE_STORE
}

// sum 5 partials; write init AND both state copies (aliasing OK: per-thread read-then-write)
__global__ __launch_bounds__(256) void combine5(
    const float4v* a, const float4v* b, const float4v* c, const float4v* d, const float4v* e,
    float4v* o_init, float4v* o_s0, float4v* o_s1, int n4)
{
  int i = blockIdx.x * 256 + threadIdx.x;
  if (i >= n4) return;
  float4v x = a[i], y = b[i], z = c[i], u = d[i], v = e[i];
  float4v s = (float4v){x.x+y.x+z.x+u.x+v.x, x.y+y.y+z.y+u.y+v.y,
                        x.z+y.z+z.z+u.z+v.z, x.w+y.w+z.w+u.w+v.w};
  o_init[i] = s; o_s0[i] = s; o_s1[i] = s;
}

// ---------------- unified gather, fully unrolled over P and L ----------------
template<int L, int PP>
__device__ __forceinline__ float gath(const float* __restrict__ sect, const int* __restrict__ paths,
                                      const float* __restrict__ pw, int n, int N, int d)
{
  float pwv[L];
#pragma unroll
  for (int l = 0; l < L; ++l) pwv[l] = pw[l * 128 + d];
  float acc = 0.f;
  const int* ip0 = paths + (size_t)n * L;
#pragma unroll
  for (int p = 0; p < PP; ++p) {
    const int* ip = ip0 + (size_t)p * N * L;   // wave-uniform -> scalar loads
    int idx[L];
#pragma unroll
    for (int l = 0; l < L; ++l) idx[l] = ip[l];
#pragma unroll
    for (int l = 0; l < L; ++l)
      acc = fmaf(pwv[l], sect[(size_t)idx[l] * 128 + d], acc);
  }
  return acc;
}

template<int LMM, int LMD, int PP>
__global__ __launch_bounds__(256) void gather_all(
    const float* __restrict__ state,
    const int* __restrict__ paths_mm, const int* __restrict__ paths_dd, const int* __restrict__ paths_md,
    const float* __restrict__ pw1l, const float* __restrict__ pw2l,
    float* __restrict__ r, int Nm, int Nd)
{
  const int d = threadIdx.x & 127;
  const int nsub = threadIdx.x >> 7;
  const int g = blockIdx.x * 2 + nsub;
  const int Nt = Nm + Nd;
  if (g >= 2 * Nt) return;
  float acc;
  if (g < Nm)
    acc = gath<LMM, PP>(state, paths_mm, pw1l, g, Nm, d);
  else if (g < Nt)
    acc = gath<LMM, PP>(state + (size_t)Nm * 128, paths_dd, pw1l, g - Nm, Nd, d);
  else
    acc = gath<LMD, PP>(state + (size_t)Nt * 128, paths_md, pw2l, g - Nt, Nt, d);
  r[(size_t)g * 128 + d] = acc * (1.0f / (float)PP);
}

// runtime fallback
__global__ __launch_bounds__(256) void gather_einsum_rt(
    const float* __restrict__ feats, const int* __restrict__ paths,
    const float* __restrict__ pw, float* __restrict__ r, int N, int P, int L)
{
  const int d = threadIdx.x & 127;
  const int n = blockIdx.x * 2 + (threadIdx.x >> 7);
  if (n >= N) return;
  float acc = 0.f;
  for (int p = 0; p < P; ++p) {
    const int* ip = paths + ((size_t)p * N + n) * L;
    for (int l = 0; l < L; ++l)
      acc = fmaf(pw[l * 128 + d], feats[(size_t)ip[l] * 128 + d], acc);
  }
  r[(size_t)n * 128 + d] = acc * (1.0f / (float)P);
}

// ---------------- fc layer: compile-time K=128, ILP via unroll ----------------
// state[rr] = ALPHA*init[base(rr)] + (1-ALPHA)*relu(R[rr] @ fcW), rr in [0, 2*Nt)
template<int TR>
__global__ __launch_bounds__(256) void fc_all(
    const float* __restrict__ Rm, const float* __restrict__ W,
    const float* __restrict__ initb, float* __restrict__ state, int Ntot, int Nt)
{
  const int col = threadIdx.x & 127;
  const int rh  = __builtin_amdgcn_readfirstlane((int)(threadIdx.x >> 7));
  const int row0 = blockIdx.x * (2 * TR) + rh * TR;
  const float* arow[TR];
#pragma unroll
  for (int r = 0; r < TR; ++r) {
    int rr = row0 + r; if (rr > Ntot - 1) rr = Ntot - 1;
    arow[r] = Rm + (size_t)rr * 128;
  }
  float acc[TR];
#pragma unroll
  for (int r = 0; r < TR; ++r) acc[r] = 0.f;
#pragma unroll 4
  for (int k = 0; k < 128; k += 8) {
    float w[8];
#pragma unroll
    for (int kk = 0; kk < 8; ++kk) w[kk] = W[(size_t)(k + kk) * 128 + col];
#pragma unroll
    for (int r = 0; r < TR; ++r) {
      const float* ap = arow[r] + k;
#pragma unroll
      for (int kk = 0; kk < 8; ++kk) acc[r] = fmaf(ap[kk], w[kk], acc[r]);
    }
  }
#pragma unroll
  for (int r = 0; r < TR; ++r) {
    int rr = row0 + r;
    if (rr < Ntot) {
      int rbase = (rr < Nt) ? rr : rr - Nt;
      state[(size_t)rr * 128 + col] =
          ALPHA_ * initb[(size_t)rbase * 128 + col] + (1.f - ALPHA_) * fmaxf(acc[r], 0.f);
    }
  }
}

// MLP collapse (ILP-4)
__global__ void collapse1(const float* __restrict__ W0, const float* __restrict__ b0,
                          const float* __restrict__ W1, const float* __restrict__ b1,
                          float* __restrict__ w01, float* __restrict__ b01,
                          int E, int K0, int H1)
{
  int row = blockIdx.x; int c = threadIdx.x;
  if (c >= H1) return;
  const float* src; float base;
  if (row < E) { src = W0 + (size_t)row * K0; base = 0.f; }
  else         { src = b0; base = b1[c]; }
  float a0 = 0.f, a1 = 0.f, a2 = 0.f, a3 = 0.f;
#pragma unroll 4
  for (int k = 0; k < K0; k += 4) {
    a0 = fmaf(src[k + 0], W1[(size_t)(k + 0) * H1 + c], a0);
    a1 = fmaf(src[k + 1], W1[(size_t)(k + 1) * H1 + c], a1);
    a2 = fmaf(src[k + 2], W1[(size_t)(k + 2) * H1 + c], a2);
    a3 = fmaf(src[k + 3], W1[(size_t)(k + 3) * H1 + c], a3);
  }
  float acc = base + ((a0 + a1) + (a2 + a3));
  if (row < E) w01[(size_t)row * H1 + c] = acc; else b01[c] = acc;
}

__global__ void collapse2(const float* __restrict__ w01, const float* __restrict__ b01,
                          const float* __restrict__ W2, const float* __restrict__ b2,
                          float* __restrict__ w512, float* __restrict__ csc,
                          int E, int H1)
{
  int i = blockIdx.x * blockDim.x + threadIdx.x;
  if (i < E) {
    float a0 = 0.f, a1 = 0.f, a2 = 0.f, a3 = 0.f;
    for (int j = 0; j < H1; j += 4) {
      a0 = fmaf(w01[(size_t)i * H1 + j + 0], W2[j + 0], a0);
      a1 = fmaf(w01[(size_t)i * H1 + j + 1], W2[j + 1], a1);
      a2 = fmaf(w01[(size_t)i * H1 + j + 2], W2[j + 2], a2);
      a3 = fmaf(w01[(size_t)i * H1 + j + 3], W2[j + 3], a3);
    }
    w512[i] = (a0 + a1) + (a2 + a3);
  } else if (i == E) {
    float a = b2[0];
    for (int j = 0; j < H1; ++j) a = fmaf(b01[j], W2[j], a);
    csc[0] = a;
  }
}

__global__ __launch_bounds__(256) void node_partial(
    const float* __restrict__ Fmm, const float* __restrict__ Fdd, const float* __restrict__ Fmd,
    const float* __restrict__ w512, float* __restrict__ uv, int Nm, int Nt)
{
  int gid = blockIdx.x * blockDim.x + threadIdx.x;
  int wid = gid >> 6;
  int lane = threadIdx.x & 63;
  if (wid >= Nt) return;
  bool isM = wid < Nm;
  const float* X = isM ? (Fmm + (size_t)wid * 128) : (Fdd + (size_t)(wid - Nm) * 128);
  const float* Y = Fmd + (size_t)wid * 128;
  const float* w1 = w512 + (isM ? 0 : 256);
  const float* w2 = w1 + 128;
  float s = fmaf(X[lane], w1[lane], 0.f);
  s = fmaf(X[lane + 64], w1[lane + 64], s);
  s = fmaf(Y[lane], w2[lane], s);
  s = fmaf(Y[lane + 64], w2[lane + 64], s);
#pragma unroll
  for (int off = 32; off > 0; off >>= 1) s += __shfl_down(s, off);
  if (lane == 0) uv[wid] = s;
}

__global__ __launch_bounds__(256) void score_kernel(
    const int* __restrict__ samples, const float* __restrict__ u, const float* __restrict__ v,
    const float* __restrict__ csc, float* __restrict__ out, int S)
{
  int s = blockIdx.x * blockDim.x + threadIdx.x;
  if (s >= S) return;
  const int2 ij = ((const int2*)samples)[s];
  float x = u[ij.x] + v[ij.y] + csc[0];
  out[s] = 1.0f / (1.0f + expf(-x));
}

extern "C" void kernel_launch(void* const* d_in, const int* in_sizes, int n_in,
                              void* d_out, int out_size, void* d_ws, size_t ws_size,
                              hipStream_t stream)
{
  const int*   paths_mm = (const int*)d_in[0];
  const int*   paths_dd = (const int*)d_in[1];
  const int*   paths_md = (const int*)d_in[2];
  const float* miRNA    = (const float*)d_in[3];
  const float* disease  = (const float*)d_in[4];
  const int*   samples  = (const int*)d_in[5];
  const float* Wm  = (const float*)d_in[6];
  const float* Wd  = (const float*)d_in[7];
  const float* pw1 = (const float*)d_in[8];
  const float* pw2 = (const float*)d_in[9];
  const float* fcW = (const float*)d_in[10];
  const float* W0  = (const float*)d_in[11];
  const float* b0  = (const float*)d_in[12];
  const float* W1  = (const float*)d_in[13];
  const float* b1  = (const float*)d_in[14];
  const float* W2  = (const float*)d_in[15];
  const float* b2  = (const float*)d_in[16];

  const int D  = 128;
  const int Nm = in_sizes[6] / D;
  const int Nd = in_sizes[7] / D;
  const int Nt = Nm + Nd;
  const int S  = in_sizes[5] / 2;
  const int layers = in_sizes[10] / (D * D);
  const int L1 = in_sizes[8] / (layers * D);
  const int L2 = in_sizes[9] / (layers * D);
  const int P  = in_sizes[0] / (Nm * L1);
  const int E  = 4 * D;
  const int K0 = in_sizes[12];
  const int H1 = in_sizes[14];
  const int Kpm = cdiv(Nm, 64) * 64;   // 8000
  const int Kpd = cdiv(Nd, 64) * 64;   // 6016

  float* out = (float*)d_out;
  float* ws  = (float*)d_ws;
  size_t off = 0;
  float* init  = ws + off; off += (size_t)Nt * D;       // summed init feats (m;d)
  float* state = ws + off; off += (size_t)2 * Nt * D;   // [mm(Nm); dd(Nd); md(Nt)]
  float* bufR  = ws + off; off += (size_t)2 * Nt * D;   // gather output
  float* w01   = ws + off; off += (size_t)E * H1;
  float* b01   = ws + off; off += H1;
  float* w512  = ws + off; off += E;
  float* csc   = ws + off; off += 1;
  float* uv    = ws + off; off += Nt;
  __hip_bfloat16* WtTm = (__hip_bfloat16*)(ws + off); off += (size_t)D * Kpm / 2;
  __hip_bfloat16* WtTd = (__hip_bfloat16*)(ws + off); off += (size_t)D * Kpd / 2;
  (void)ws_size; (void)n_in; (void)out_size;

  // 1. tiled+swizzled bf16 weight transposes (coalesced via LDS tile transpose)
  {
    dim3 g1(Kpm / 64, 4); make_wtT<<<g1, 256, 0, stream>>>(Wm, WtTm, Nm);
    dim3 g2(Kpd / 64, 4); make_wtT<<<g2, 256, 0, stream>>>(Wd, WtTd, Nd);
  }

  // 2. MLP collapse (independent of features)
  collapse1<<<E + 1, 64, 0, stream>>>(W0, b0, W1, b1, w01, b01, E, K0, H1);
  collapse2<<<cdiv(E + 1, 256), 256, 0, stream>>>(w01, b01, W2, b2, w512, csc, E, H1);

  // 3. init GEMMs: 128-row tiles, W DMA'd from pre-swizzled WtT, split-K=5
  {
    constexpr int KSPLIT = 5;
    int nbm = cdiv(Nm, 128), nbd = cdiv(Nd, 128);
    init_mfma_lds<KSPLIT><<<(nbm + nbd) * KSPLIT, 512, 0, stream>>>(
        miRNA, WtTm, Nm, nbm, disease, WtTd, Nd, Kpd,
        init, state, state + (size_t)Nt * D, bufR, bufR + (size_t)Nt * D);
    int n4 = Nt * D / 4;
    combine5<<<cdiv(n4, 256), 256, 0, stream>>>(
        (const float4v*)init, (const float4v*)state, (const float4v*)(state + (size_t)Nt * D),
        (const float4v*)bufR, (const float4v*)(bufR + (size_t)Nt * D),
        (float4v*)init, (float4v*)state, (float4v*)(state + (size_t)Nt * D), n4);
  }

  // 4. fused path-layer chains
  constexpr int TR = 8;
  for (int l = 0; l < layers; ++l) {
    const float* pw1l = pw1 + (size_t)l * L1 * D;
    const float* pw2l = pw2 + (size_t)l * L2 * D;
    if (L1 == 4 && L2 == 6 && P == 8) {
      gather_all<4, 6, 8><<<Nt, 256, 0, stream>>>(
          state, paths_mm, paths_dd, paths_md, pw1l, pw2l, bufR, Nm, Nd);
    } else {
      gather_einsum_rt<<<cdiv(Nm, 2), 256, 0, stream>>>(state, paths_mm, pw1l, bufR, Nm, P, L1);
      gather_einsum_rt<<<cdiv(Nd, 2), 256, 0, stream>>>(state + (size_t)Nm * D, paths_dd, pw1l,
                                                        bufR + (size_t)Nm * D, Nd, P, L1);
      gather_einsum_rt<<<cdiv(Nt, 2), 256, 0, stream>>>(state + (size_t)Nt * D, paths_md, pw2l,
                                                        bufR + (size_t)Nt * D, Nt, P, L2);
    }
    fc_all<TR><<<cdiv(2 * Nt, 2 * TR), 256, 0, stream>>>(
        bufR, fcW + (size_t)l * D * D, init, state, 2 * Nt, Nt);
  }

  // 5. per-node partial dots + scoring
  node_partial<<<cdiv(Nt * 64, 256), 256, 0, stream>>>(
      state, state + (size_t)Nm * D, state + (size_t)Nt * D, w512, uv, Nm, Nt);
  score_kernel<<<cdiv(S, 256), 256, 0, stream>>>(samples, uv, uv + Nm, csc, out, S);
}